// Round 1
// baseline (245.082 us; speedup 1.0000x reference)
//
#include <hip/hip_runtime.h>

// N=4096, D=1024 self-attention, all GEMMs NT-form bf16 MFMA (16x16x32), fp32 acc.
// R4: BK=64 + XOR swizzle -> 0 bank conflicts. R5: XCD swizzle. R6: k_pv BK=128.
// R7: softmax fused into epilogues. R11: rowsum @ ws+64MB via cvt_all.
// R12: V-transpose fused into k_qkv (MODE 3). R13: k_score 256x128 tile.
// R14: counted-vmcnt ring pipeline (T3+T4+T5) for k_score + k_pv:
//   512-thread 8-wave blocks, BK=32, RING=4 LDS slots, stage tile t+2 while
//   computing tile t, s_waitcnt vmcnt(LPT) once per tile (never 0 mid-loop),
//   2 phases/tile with setprio(1) around MFMA clusters.
//   k_score: 256x256 tile, grid 16x16=256 (1 blk/CU, 128KB LDS).
//   k_pv:    256x128 tile, split-K=2 (atomicAdd merge; out zeroed in cvt_all),
//            grid 8x16x2=256 (1 blk/CU, 96KB LDS). Halves k_pv L2 staging
//            traffic (768->384MB) vs old 128x64 tile.
//
// ws layout:
//   Qb bf16[4096,1024] @ 0      Kb @ 8MB     Vt bf16[1024,4096] @ 24MB
//   SP bf16[4096,4096] @ 32MB   (exp'd scores; spans 32..64MB)
//   xb @ 32MB (overlaps SP; dead before k_score), Wqb @ 40MB, Wkb @ 42MB, Wvb @ 44MB
//   rowsum fp32[4096] @ 64MB    (past SP; ws_size >= 112MB proven in R3)

#define N_TOK 4096
#define DDIM  1024

typedef short s16x4 __attribute__((ext_vector_type(4)));
typedef short s16x8 __attribute__((ext_vector_type(8)));
typedef float f32x4 __attribute__((ext_vector_type(4)));

#define VMCNT0() asm volatile("s_waitcnt vmcnt(0)" ::: "memory")
#define VMCNT3() asm volatile("s_waitcnt vmcnt(3)" ::: "memory")
#define VMCNT4() asm volatile("s_waitcnt vmcnt(4)" ::: "memory")
#define BARRIER() do { asm volatile("" ::: "memory"); \
                       __builtin_amdgcn_s_barrier();  \
                       asm volatile("" ::: "memory"); } while (0)

__device__ inline short f2b(float f) {
  unsigned int u = __float_as_uint(f);
  unsigned int r = (u + 0x7FFFu + ((u >> 16) & 1u)) >> 16;
  return (short)(unsigned short)r;
}

__device__ __forceinline__ void gld_lds16(const short* g, short* l) {
  __builtin_amdgcn_global_load_lds(
      (const __attribute__((address_space(1))) unsigned int*)g,
      (__attribute__((address_space(3))) unsigned int*)l, 16, 0, 0);
}

// XCD-locality remap, GY=32 grids: XCD (L%8) owns a 4-row-tile band.
__device__ __forceinline__ void xcd_remap(int gx, int& bx, int& by) {
  const int L = by * gx + bx;
  const int g = L & 7, h = L >> 3;
  by = g * 4 + (h & 3);
  bx = h >> 2;
}
// 256-row-tile variant: XCD owns a 2-row-tile band. gx = gridDim.x.
__device__ __forceinline__ void xcd_remap16(int gx, int& bx, int& by) {
  const int L = by * gx + bx;
  const int g = L & 7, h = L >> 3;
  by = g * 2 + (h & 1);
  bx = h >> 1;
}

// ---------------------------------------------------------------------------
// Legacy 2-phase core (kept for k_qkv). MODE 0: bf16 store scale*acc+bias;
// MODE 3: bf16 TRANSPOSED store of acc + bias.
// ---------------------------------------------------------------------------
template<int BM, int BN, int BK, int MODE>
constexpr int lds_shorts() {
  return (MODE == 3 && BN * 136 > BM * BK + BN * BK) ? BN * 136
                                                     : BM * BK + BN * BK;
}

template<int BM, int BN, int BK, int MODE>
__device__ __forceinline__ void gemm_core(
    const short* __restrict__ A, const short* __restrict__ B,
    void* __restrict__ C, float* __restrict__ aux, short* smem,
    int K, int ld, int ldc, float scale, int row0, int col0)
{
  constexpr int WM = BM / 2, WN = BN / 2, AI = WM / 16, AJ = WN / 16;
  constexpr int CPR = BK / 8;
  constexpr int MASK = CPR - 1;
  constexpr int CA = BM * CPR / 256;
  constexpr int CB = BN * CPR / 256;
  constexpr int NH = BK / 32;
  short* As = smem;
  short* Bs = smem + BM * BK;

  const int tid  = threadIdx.x;
  const int wave = tid >> 6, lane = tid & 63;
  const int wm = wave >> 1, wn = wave & 1;
  const int quad = lane >> 4, lr = lane & 15;

  f32x4 acc[AI][AJ];
  #pragma unroll
  for (int i = 0; i < AI; i++)
    #pragma unroll
    for (int j = 0; j < AJ; j++) acc[i][j] = {0.f, 0.f, 0.f, 0.f};

  for (int kk = 0; kk < K; kk += BK) {
    __syncthreads();
    #pragma unroll
    for (int c = 0; c < CA; c++) {
      const int id = c * 256 + wave * 64 + lane;
      const int r = id / CPR, slot = id & MASK;
      const int q = slot ^ (r & MASK);
      gld_lds16(A + (size_t)(row0 + r) * ld + kk + q * 8,
                &As[(c * 256 + wave * 64) * 8]);
    }
    #pragma unroll
    for (int c = 0; c < CB; c++) {
      const int id = c * 256 + wave * 64 + lane;
      const int r = id / CPR, slot = id & MASK;
      const int q = slot ^ (r & MASK);
      gld_lds16(B + (size_t)(col0 + r) * ld + kk + q * 8,
                &Bs[(c * 256 + wave * 64) * 8]);
    }
    __syncthreads();

    #pragma unroll
    for (int h = 0; h < NH; h++) {
      s16x8 af[AI], bf[AJ];
      #pragma unroll
      for (int i = 0; i < AI; i++) {
        const int row = wm * WM + i * 16 + lr;
        const int ch = (h * 4 + quad) ^ (row & MASK);
        af[i] = *reinterpret_cast<const s16x8*>(&As[(row * CPR + ch) * 8]);
      }
      #pragma unroll
      for (int j = 0; j < AJ; j++) {
        const int row = wn * WN + j * 16 + lr;
        const int ch = (h * 4 + quad) ^ (row & MASK);
        bf[j] = *reinterpret_cast<const s16x8*>(&Bs[(row * CPR + ch) * 8]);
      }
      #pragma unroll
      for (int i = 0; i < AI; i++)
        #pragma unroll
        for (int j = 0; j < AJ; j++)
          acc[i][j] = __builtin_amdgcn_mfma_f32_16x16x32_bf16(af[i], bf[j], acc[i][j], 0, 0, 0);
    }
  }

  if constexpr (MODE == 0) {
    float bb[AJ];
    #pragma unroll
    for (int j = 0; j < AJ; j++) bb[j] = aux[col0 + wn * WN + j * 16 + lr];
    #pragma unroll
    for (int i = 0; i < AI; i++) {
      const int r0 = row0 + wm * WM + i * 16 + quad * 4;
      #pragma unroll
      for (int j = 0; j < AJ; j++) {
        const int c = col0 + wn * WN + j * 16 + lr;
        #pragma unroll
        for (int r = 0; r < 4; r++)
          ((short*)C)[(size_t)(r0 + r) * ldc + c] = f2b(acc[i][j][r] * scale + bb[j]);
      }
    }
  } else {
    // MODE 3: transposed bf16 store with bias. trans[col][row], stride 136.
    float bb[AJ];
    #pragma unroll
    for (int j = 0; j < AJ; j++) bb[j] = aux[col0 + wn * WN + j * 16 + lr];
    __syncthreads();
    short* trans = smem;      // BN x 136 shorts
    #pragma unroll
    for (int i = 0; i < AI; i++) {
      const int rl = wm * WM + i * 16 + quad * 4;
      #pragma unroll
      for (int j = 0; j < AJ; j++) {
        const int cl = wn * WN + j * 16 + lr;
        s16x4 v;
        #pragma unroll
        for (int r = 0; r < 4; r++) v[r] = f2b(acc[i][j][r] * scale + bb[j]);
        *reinterpret_cast<s16x4*>(&trans[cl * 136 + rl]) = v;
      }
    }
    __syncthreads();
    #pragma unroll
    for (int s = 0; s < BM * BN / 8 / 256; s++) {
      const int u = s * 256 + tid;
      const int cc = u >> (31 - __builtin_clz(BM / 8));
      const int seg = u & (BM / 8 - 1);
      s16x8 v = *reinterpret_cast<const s16x8*>(&trans[cc * 136 + seg * 8]);
      *reinterpret_cast<s16x8*>(
          &((short*)C)[(size_t)(cc + col0) * ldc + row0 + seg * 8]) = v;
    }
  }
}

// ---------------------------------------------------------------------------
// R14 ring-pipelined GEMM: 512 threads (8 waves, 2x4), BK=32, RING LDS slots.
// Stage tile t+2 while computing tile t; vmcnt(LPT) once per tile keeps the
// next tile's loads in flight across barriers (T4). 2 phases/tile, setprio(1)
// around each MFMA cluster (T5). Chunk swizzle q = slot ^ (r&3) ^ ((r>>2)&3)
// -> conflict-free ds_read_b128 at 64B row stride.
// MODE 1: bf16 store exp(scale*acc) + rowsum atomics   (aux = rowsum)
// MODE 4: atomicAdd(out, acc / rowsum[row])            (aux = rowsum)
// ---------------------------------------------------------------------------
template<int BM, int BN, int RING, int LPT, int MODE>
__device__ __forceinline__ void gemm_ring(
    const short* __restrict__ A, const short* __restrict__ B,
    void* __restrict__ C, float* __restrict__ aux, short* smem,
    int K, int ld, int ldc, float scale, int row0, int col0)
{
  constexpr int BK = 32;
  constexpr int WM = BM / 2, WN = BN / 4;
  constexpr int AI = WM / 16, AJ = WN / 16, AH = AI / 2;
  constexpr int SLOT = (BM + BN) * BK;
  constexpr int ACH = BM * (BK / 8);          // # A chunks (multiple of 512)
  static_assert((BM + BN) * (BK / 8) == LPT * 512, "LPT mismatch");
  static_assert(ACH % 512 == 0, "A/B staging boundary must be wave-aligned");

  const int tid  = threadIdx.x;
  const int wave = tid >> 6, lane = tid & 63;
  const int wm = wave >> 2, wn = wave & 3;
  const int quad = lane >> 4, lr = lane & 15;
  const int ph8 = ((quad ^ (lr & 3) ^ ((lr >> 2) & 3)) * 8);  // frag chunk

  f32x4 acc[AI][AJ];
  #pragma unroll
  for (int i = 0; i < AI; i++)
    #pragma unroll
    for (int j = 0; j < AJ; j++) acc[i][j] = {0.f, 0.f, 0.f, 0.f};

  const int NT = K / BK;

  auto stage = [&](int t, int s, int c) {
    const int id = c * 512 + tid;
    const int r = id >> 2;
    const int q = (id & 3) ^ (r & 3) ^ ((r >> 2) & 3);
    const short* src = (id < ACH)
        ? A + (size_t)(row0 + r) * ld + t * BK + q * 8
        : B + (size_t)(col0 + r - BM) * ld + t * BK + q * 8;
    gld_lds16(src, &smem[s * SLOT + (c * 512 + wave * 64) * 8]);
  };

  // prologue: tiles 0 and 1 into slots 0,1; wait for tile 0 only.
  #pragma unroll
  for (int c = 0; c < LPT; c++) stage(0, 0, c);
  #pragma unroll
  for (int c = 0; c < LPT; c++) stage(1, 1, c);
  if constexpr (LPT == 3) VMCNT3(); else VMCNT4();
  BARRIER();

  int slot = 0;
  for (int t = 0; t < NT; t++) {
    const short* sA = &smem[slot * SLOT];
    const short* sB = sA + BM * BK;
    const bool pf = (t + 2) < NT;
    int s2 = slot + 2; if (s2 >= RING) s2 -= RING;

    s16x8 bf[AJ], af[AH];
    #pragma unroll
    for (int j = 0; j < AJ; j++) {
      const int row = wn * WN + j * 16 + lr;
      bf[j] = *reinterpret_cast<const s16x8*>(&sB[row * BK + ph8]);
    }
    #pragma unroll
    for (int i = 0; i < AH; i++) {
      const int row = wm * WM + i * 16 + lr;
      af[i] = *reinterpret_cast<const s16x8*>(&sA[row * BK + ph8]);
    }
    if (pf) { stage(t + 2, s2, 0); stage(t + 2, s2, 1); }
    BARRIER();
    __builtin_amdgcn_s_setprio(1);
    #pragma unroll
    for (int i = 0; i < AH; i++)
      #pragma unroll
      for (int j = 0; j < AJ; j++)
        acc[i][j] = __builtin_amdgcn_mfma_f32_16x16x32_bf16(af[i], bf[j], acc[i][j], 0, 0, 0);
    __builtin_amdgcn_s_setprio(0);
    BARRIER();

    #pragma unroll
    for (int i = 0; i < AH; i++) {
      const int row = wm * WM + (AH + i) * 16 + lr;
      af[i] = *reinterpret_cast<const s16x8*>(&sA[row * BK + ph8]);
    }
    if (pf) {
      stage(t + 2, s2, 2);
      if constexpr (LPT == 4) stage(t + 2, s2, 3);
    }
    BARRIER();
    __builtin_amdgcn_s_setprio(1);
    #pragma unroll
    for (int i = 0; i < AH; i++)
      #pragma unroll
      for (int j = 0; j < AJ; j++)
        acc[AH + i][j] = __builtin_amdgcn_mfma_f32_16x16x32_bf16(af[i], bf[j], acc[AH + i][j], 0, 0, 0);
    __builtin_amdgcn_s_setprio(0);
    // drain exactly up to tile t+1; keep tile t+2's LPT loads in flight.
    if (pf) { if constexpr (LPT == 3) VMCNT3(); else VMCNT4(); }
    else    { VMCNT0(); }
    BARRIER();
    slot++; if (slot == RING) slot = 0;
  }

  if constexpr (MODE == 1) {
    #pragma unroll
    for (int i = 0; i < AI; i++) {
      const int r0 = row0 + wm * WM + i * 16 + quad * 4;
      float ex[AJ][4];
      #pragma unroll
      for (int j = 0; j < AJ; j++) {
        const int c = col0 + wn * WN + j * 16 + lr;
        #pragma unroll
        for (int r = 0; r < 4; r++) {
          ex[j][r] = __expf(acc[i][j][r] * scale);
          ((short*)C)[(size_t)(r0 + r) * ldc + c] = f2b(ex[j][r]);
        }
      }
      #pragma unroll
      for (int r = 0; r < 4; r++) {
        float s = 0.f;
        #pragma unroll
        for (int j = 0; j < AJ; j++) s += ex[j][r];
        s += __shfl_xor(s, 1, 64);
        s += __shfl_xor(s, 2, 64);
        s += __shfl_xor(s, 4, 64);
        s += __shfl_xor(s, 8, 64);
        if (lr == 0) atomicAdd(&aux[r0 + r], s);
      }
    }
  } else {
    // MODE 4: split-K merge. out += acc * (1/rowsum[row]).
    #pragma unroll
    for (int i = 0; i < AI; i++) {
      const int r0 = row0 + wm * WM + i * 16 + quad * 4;
      float linv[4];
      #pragma unroll
      for (int r = 0; r < 4; r++) linv[r] = 1.0f / aux[r0 + r];
      #pragma unroll
      for (int j = 0; j < AJ; j++) {
        const int c = col0 + wn * WN + j * 16 + lr;
        #pragma unroll
        for (int r = 0; r < 4; r++)
          atomicAdd(&((float*)C)[(size_t)(r0 + r) * ldc + c],
                    acc[i][j][r] * linv[r]);
      }
    }
  }
}

// ---------------------------------------------------------------------------
// fp32 -> bf16 conversion for x, Wq, Wk, Wv + rowsum/out zeroing (one launch).
// ---------------------------------------------------------------------------
#define XU  (N_TOK * DDIM / 8)      // 524288
#define WU  (DDIM * DDIM / 8)       // 131072
#define NCVT ((XU + 3 * WU) / 256)  // 3584 convert blocks
#define NZB  1024                   // out-zero blocks (16MB, for split-K pv)
__global__ __launch_bounds__(256)
void cvt_all(const float* __restrict__ x,  const float* __restrict__ wq,
             const float* __restrict__ wk, const float* __restrict__ wv,
             short* __restrict__ xb, short* __restrict__ wqb,
             short* __restrict__ wkb, short* __restrict__ wvb,
             float* __restrict__ rowsum, float* __restrict__ outz)
{
  if (blockIdx.x >= NCVT) {
    const int zb = blockIdx.x - NCVT;
    float4 z = {0.f, 0.f, 0.f, 0.f};
    if (zb < NZB) {
      float4* p = reinterpret_cast<float4*>(outz) +
                  (size_t)zb * 1024 + threadIdx.x * 4;
      p[0] = z; p[1] = z; p[2] = z; p[3] = z;
    } else {
      float4* p = reinterpret_cast<float4*>(rowsum) + threadIdx.x * 4;
      p[0] = z; p[1] = z; p[2] = z; p[3] = z;
    }
    return;
  }
  int gid = blockIdx.x * 256 + threadIdx.x;
  const float* src; short* dst; int off;
  if (gid < XU)               { src = x;  dst = xb;  off = gid; }
  else if (gid < XU + WU)     { src = wq; dst = wqb; off = gid - XU; }
  else if (gid < XU + 2 * WU) { src = wk; dst = wkb; off = gid - XU - WU; }
  else                        { src = wv; dst = wvb; off = gid - XU - 2 * WU; }
  const float4* g = reinterpret_cast<const float4*>(src) + (size_t)off * 2;
  float4 a = g[0], b = g[1];
  s16x8 o;
  o[0] = f2b(a.x); o[1] = f2b(a.y); o[2] = f2b(a.z); o[3] = f2b(a.w);
  o[4] = f2b(b.x); o[5] = f2b(b.y); o[6] = f2b(b.z); o[7] = f2b(b.w);
  reinterpret_cast<s16x8*>(dst)[off] = o;
}

// ---------------------------------------------------------------------------
// GEMM kernels
// ---------------------------------------------------------------------------
__global__ __launch_bounds__(256)
void k_qkv(const short* __restrict__ xb,
           const short* __restrict__ Wqb, const short* __restrict__ Wkb,
           const short* __restrict__ Wvb,
           const float* __restrict__ bq, const float* __restrict__ bk,
           const float* __restrict__ bv,
           short* __restrict__ Qb, short* __restrict__ Kb, short* __restrict__ Vt)
{
  __shared__ short smem[lds_shorts<128, 128, 64, 3>()];   // 17408 shorts
  int bx = blockIdx.x, by = blockIdx.y;
  xcd_remap(DDIM / 128, bx, by);
  if (blockIdx.z == 0) {
    gemm_core<128, 128, 64, 0>(xb, Wqb, Qb, (float*)bq, smem, DDIM, DDIM, DDIM,
                               1.0f, by * 128, bx * 128);
  } else if (blockIdx.z == 1) {
    gemm_core<128, 128, 64, 0>(xb, Wkb, Kb, (float*)bk, smem, DDIM, DDIM, DDIM,
                               1.0f, by * 128, bx * 128);
  } else {
    gemm_core<128, 128, 64, 3>(xb, Wvb, Vt, (float*)bv, smem, DDIM, DDIM, N_TOK,
                               1.0f, by * 128, bx * 128);
  }
}

// 256x256 score tile, ring pipeline; grid 16x16 = 256 = 1/CU, 128KB LDS.
__global__ __launch_bounds__(512, 2)
void k_score(const short* __restrict__ Qb, const short* __restrict__ Kb,
             short* __restrict__ SP, float* __restrict__ rowsum)
{
  __shared__ short smem[4 * (256 + 256) * 32];            // 128 KiB
  int bx = blockIdx.x, by = blockIdx.y;
  xcd_remap16(16, bx, by);
  gemm_ring<256, 256, 4, 4, 1>(Qb, Kb, SP, rowsum, smem, DDIM, DDIM, N_TOK,
                               0.03125f, by * 256, bx * 256);
}

// 256x128 pv tile, ring pipeline, split-K=2; grid 8x16x2 = 256 = 1/CU, 96KB.
__global__ __launch_bounds__(512, 2)
void k_pv(const short* __restrict__ SP, const short* __restrict__ Vt,
          float* __restrict__ out, const float* __restrict__ rowsum)
{
  __shared__ short smem[4 * (256 + 128) * 32];            // 96 KiB
  int bx = blockIdx.x, by = blockIdx.y;
  xcd_remap16(8, bx, by);
  const int k0 = blockIdx.z * (N_TOK / 2);
  gemm_ring<256, 128, 4, 3, 4>(SP + k0, Vt + k0, out, (float*)rowsum, smem,
                               N_TOK / 2, N_TOK, DDIM, 1.0f, by * 256, bx * 128);
}

// ---------------------------------------------------------------------------
extern "C" void kernel_launch(void* const* d_in, const int* in_sizes, int n_in,
                              void* d_out, int out_size, void* d_ws, size_t ws_size,
                              hipStream_t stream)
{
  const float* x  = (const float*)d_in[0];
  const float* Wq = (const float*)d_in[1];
  const float* bq = (const float*)d_in[2];
  const float* Wk = (const float*)d_in[3];
  const float* bk = (const float*)d_in[4];
  const float* Wv = (const float*)d_in[5];
  const float* bv = (const float*)d_in[6];
  float* out = (float*)d_out;

  char* ws = (char*)d_ws;
  const size_t MB = 1024 * 1024;
  short* Qb  = (short*)(ws + 0 * MB);
  short* Kb  = (short*)(ws + 8 * MB);
  short* Vt  = (short*)(ws + 24 * MB);
  short* SP  = (short*)(ws + 32 * MB);   // 32 MB (32..64MB)
  short* xb  = (short*)(ws + 32 * MB);   // overlaps SP (dead before k_score)
  short* Wqb = (short*)(ws + 40 * MB);
  short* Wkb = (short*)(ws + 42 * MB);
  short* Wvb = (short*)(ws + 44 * MB);
  float* rowsum = (float*)(ws + 64 * MB); // past SP (ws >= 112MB, proven R3)

  dim3 b256(256), b512(512);

  // fp32 -> bf16 for x and the three W's + zero rowsum and out
  cvt_all<<<dim3(NCVT + NZB + 1), b256, 0, stream>>>(
      x, Wq, Wk, Wv, xb, Wqb, Wkb, Wvb, rowsum, out);

  // Q/K = x @ W^T + b (bf16); V-slice writes Vt transposed directly
  k_qkv<<<dim3(DDIM / 128, N_TOK / 128, 3), b256, 0, stream>>>(
      xb, Wqb, Wkb, Wvb, bq, bk, bv, Qb, Kb, Vt);

  // P = exp(Q @ K^T / 32) (bf16) + rowsum atomics; ring-pipelined 256x256
  k_score<<<dim3(N_TOK / 256, N_TOK / 256), b512, 0, stream>>>(
      Qb, Kb, SP, rowsum);

  // O += (P @ Vt^T) / rowsum (fp32 atomics), ring-pipelined 256x128, split-K=2
  k_pv<<<dim3(DDIM / 128, N_TOK / 256, 2), b512, 0, stream>>>(
      SP, Vt, out, rowsum);
}

// Round 2
// 229.671 us; speedup vs baseline: 1.0671x; 1.0671x over previous
//
#include <hip/hip_runtime.h>

// N=4096, D=1024 self-attention, all GEMMs NT-form bf16 MFMA (16x16x32), fp32 acc.
// R4: BK=64 + XOR swizzle -> 0 bank conflicts. R5: XCD swizzle. R6: k_pv BK=128.
// R7: softmax fused into k_score/k_pv epilogues. R11: rowsum @ ws+64MB via cvt_all.
// R12: V-transpose fused into k_qkv (MODE 3). R13: k_score 256x128 tile.
// R14 (REVERTED): BK=32 ring pipeline regressed both attention GEMMs ~30%
//   (thin phases, 1 blk/CU residency loss, 5.2M LDS conflicts). Lesson: keep
//   the proven 2-phase core; change one variable at a time.
// R15: k_pv rebuilt as 128x128 BK=64 (same proven m97-style inner loop as
//   k_qkv; MFMA:load 4:1 vs old 2.67:1) with split-K=2 -> grid (8,32,2)=512
//   = 2 blk/CU. Merge via fp32 atomicAdd into out (MODE 4); out zeroed in
//   cvt_all. Per-block staging traffic 805->537MB, barriers/FLOP halved.
//
// ws layout:
//   Qb bf16[4096,1024] @ 0      Kb @ 8MB     Vt bf16[1024,4096] @ 24MB
//   SP bf16[4096,4096] @ 32MB   (exp'd scores; spans 32..64MB)
//   xb @ 32MB (overlaps SP; dead before k_score), Wqb @ 40MB, Wkb @ 42MB, Wvb @ 44MB
//   rowsum fp32[4096] @ 64MB    (past SP; ws_size >= 112MB proven in R3)

#define N_TOK 4096
#define DDIM  1024

typedef short s16x4 __attribute__((ext_vector_type(4)));
typedef short s16x8 __attribute__((ext_vector_type(8)));
typedef float f32x4 __attribute__((ext_vector_type(4)));

__device__ inline short f2b(float f) {
  unsigned int u = __float_as_uint(f);
  unsigned int r = (u + 0x7FFFu + ((u >> 16) & 1u)) >> 16;
  return (short)(unsigned short)r;
}

__device__ __forceinline__ void gld_lds16(const short* g, short* l) {
  __builtin_amdgcn_global_load_lds(
      (const __attribute__((address_space(1))) unsigned int*)g,
      (__attribute__((address_space(3))) unsigned int*)l, 16, 0, 0);
}

// XCD-locality remap, GY=32 grids: XCD (L%8) owns a 4-row-tile band.
__device__ __forceinline__ void xcd_remap(int gx, int& bx, int& by) {
  const int L = by * gx + bx;
  const int g = L & 7, h = L >> 3;
  by = g * 4 + (h & 3);
  bx = h >> 2;
}
// GY=16 variant (256-row tiles): XCD owns a 2-row-tile band.
__device__ __forceinline__ void xcd_remap16(int gx, int& bx, int& by) {
  const int L = by * gx + bx;
  const int g = L & 7, h = L >> 3;
  by = g * 2 + (h & 1);
  bx = h >> 1;
}

// ---------------------------------------------------------------------------
// Core NT GEMM tile, bf16 in, fp32 acc, 16x16x32 MFMA. MODE epilogues:
//   0: bf16 store of scale*acc + bias                  (aux = bias)
//   1: bf16 store of exp(scale*acc) + rowsum atomics   (aux = rowsum)
//   2: fp32 store of acc / rowsum[row]                 (aux = rowsum)
//   3: bf16 TRANSPOSED store of acc + bias: C[col*ldc + row]  (aux = bias)
//   4: fp32 atomicAdd of acc / rowsum[row] (split-K)   (aux = rowsum)
// Caller provides smem of >= lds_shorts<...>() shorts (static per kernel).
// LDS chunk q of row r at slot q ^ (r & (BK/8-1)) -> conflict-free b128 reads.
// ---------------------------------------------------------------------------
template<int BM, int BN, int BK, int MODE>
constexpr int lds_shorts() {
  return (MODE == 3 && BN * 136 > BM * BK + BN * BK) ? BN * 136
                                                     : BM * BK + BN * BK;
}

template<int BM, int BN, int BK, int MODE>
__device__ __forceinline__ void gemm_core(
    const short* __restrict__ A, const short* __restrict__ B,
    void* __restrict__ C, float* __restrict__ aux, short* smem,
    int K, int ld, int ldc, float scale, int row0, int col0)
{
  constexpr int WM = BM / 2, WN = BN / 2, AI = WM / 16, AJ = WN / 16;
  constexpr int CPR = BK / 8;
  constexpr int MASK = CPR - 1;
  constexpr int CA = BM * CPR / 256;
  constexpr int CB = BN * CPR / 256;
  constexpr int NH = BK / 32;
  short* As = smem;
  short* Bs = smem + BM * BK;

  const int tid  = threadIdx.x;
  const int wave = tid >> 6, lane = tid & 63;
  const int wm = wave >> 1, wn = wave & 1;
  const int quad = lane >> 4, lr = lane & 15;

  f32x4 acc[AI][AJ];
  #pragma unroll
  for (int i = 0; i < AI; i++)
    #pragma unroll
    for (int j = 0; j < AJ; j++) acc[i][j] = {0.f, 0.f, 0.f, 0.f};

  for (int kk = 0; kk < K; kk += BK) {
    __syncthreads();
    #pragma unroll
    for (int c = 0; c < CA; c++) {
      const int id = c * 256 + wave * 64 + lane;
      const int r = id / CPR, slot = id & MASK;
      const int q = slot ^ (r & MASK);
      gld_lds16(A + (size_t)(row0 + r) * ld + kk + q * 8,
                &As[(c * 256 + wave * 64) * 8]);
    }
    #pragma unroll
    for (int c = 0; c < CB; c++) {
      const int id = c * 256 + wave * 64 + lane;
      const int r = id / CPR, slot = id & MASK;
      const int q = slot ^ (r & MASK);
      gld_lds16(B + (size_t)(col0 + r) * ld + kk + q * 8,
                &Bs[(c * 256 + wave * 64) * 8]);
    }
    __syncthreads();

    #pragma unroll
    for (int h = 0; h < NH; h++) {
      s16x8 af[AI], bf[AJ];
      #pragma unroll
      for (int i = 0; i < AI; i++) {
        const int row = wm * WM + i * 16 + lr;
        const int ch = (h * 4 + quad) ^ (row & MASK);
        af[i] = *reinterpret_cast<const s16x8*>(&As[(row * CPR + ch) * 8]);
      }
      #pragma unroll
      for (int j = 0; j < AJ; j++) {
        const int row = wn * WN + j * 16 + lr;
        const int ch = (h * 4 + quad) ^ (row & MASK);
        bf[j] = *reinterpret_cast<const s16x8*>(&Bs[(row * CPR + ch) * 8]);
      }
      #pragma unroll
      for (int i = 0; i < AI; i++)
        #pragma unroll
        for (int j = 0; j < AJ; j++)
          acc[i][j] = __builtin_amdgcn_mfma_f32_16x16x32_bf16(af[i], bf[j], acc[i][j], 0, 0, 0);
    }
  }

  if constexpr (MODE == 0) {
    float bb[AJ];
    #pragma unroll
    for (int j = 0; j < AJ; j++) bb[j] = aux[col0 + wn * WN + j * 16 + lr];
    #pragma unroll
    for (int i = 0; i < AI; i++) {
      const int r0 = row0 + wm * WM + i * 16 + quad * 4;
      #pragma unroll
      for (int j = 0; j < AJ; j++) {
        const int c = col0 + wn * WN + j * 16 + lr;
        #pragma unroll
        for (int r = 0; r < 4; r++)
          ((short*)C)[(size_t)(r0 + r) * ldc + c] = f2b(acc[i][j][r] * scale + bb[j]);
      }
    }
  } else if constexpr (MODE == 1) {
    #pragma unroll
    for (int i = 0; i < AI; i++) {
      const int r0 = row0 + wm * WM + i * 16 + quad * 4;
      float ex[AJ][4];
      #pragma unroll
      for (int j = 0; j < AJ; j++) {
        const int c = col0 + wn * WN + j * 16 + lr;
        #pragma unroll
        for (int r = 0; r < 4; r++) {
          ex[j][r] = __expf(acc[i][j][r] * scale);
          ((short*)C)[(size_t)(r0 + r) * ldc + c] = f2b(ex[j][r]);
        }
      }
      #pragma unroll
      for (int r = 0; r < 4; r++) {
        float s = 0.f;
        #pragma unroll
        for (int j = 0; j < AJ; j++) s += ex[j][r];
        s += __shfl_xor(s, 1, 64);
        s += __shfl_xor(s, 2, 64);
        s += __shfl_xor(s, 4, 64);
        s += __shfl_xor(s, 8, 64);
        if (lr == 0) atomicAdd(&aux[r0 + r], s);
      }
    }
  } else if constexpr (MODE == 2) {
    #pragma unroll
    for (int i = 0; i < AI; i++) {
      const int r0 = row0 + wm * WM + i * 16 + quad * 4;
      float linv[4];
      #pragma unroll
      for (int r = 0; r < 4; r++) linv[r] = 1.0f / aux[r0 + r];
      #pragma unroll
      for (int j = 0; j < AJ; j++) {
        const int c = col0 + wn * WN + j * 16 + lr;
        #pragma unroll
        for (int r = 0; r < 4; r++)
          ((float*)C)[(size_t)(r0 + r) * ldc + c] = acc[i][j][r] * linv[r];
      }
    }
  } else if constexpr (MODE == 4) {
    // split-K merge: out += acc * (1/rowsum[row]); out pre-zeroed in cvt_all.
    #pragma unroll
    for (int i = 0; i < AI; i++) {
      const int r0 = row0 + wm * WM + i * 16 + quad * 4;
      float linv[4];
      #pragma unroll
      for (int r = 0; r < 4; r++) linv[r] = 1.0f / aux[r0 + r];
      #pragma unroll
      for (int j = 0; j < AJ; j++) {
        const int c = col0 + wn * WN + j * 16 + lr;
        #pragma unroll
        for (int r = 0; r < 4; r++)
          atomicAdd(&((float*)C)[(size_t)(r0 + r) * ldc + c],
                    acc[i][j][r] * linv[r]);
      }
    }
  } else {
    // MODE 3: transposed bf16 store with bias. trans[col][row], stride 136.
    float bb[AJ];
    #pragma unroll
    for (int j = 0; j < AJ; j++) bb[j] = aux[col0 + wn * WN + j * 16 + lr];
    __syncthreads();
    short* trans = smem;      // BN x 136 shorts
    #pragma unroll
    for (int i = 0; i < AI; i++) {
      const int rl = wm * WM + i * 16 + quad * 4;
      #pragma unroll
      for (int j = 0; j < AJ; j++) {
        const int cl = wn * WN + j * 16 + lr;
        s16x4 v;
        #pragma unroll
        for (int r = 0; r < 4; r++) v[r] = f2b(acc[i][j][r] * scale + bb[j]);
        *reinterpret_cast<s16x4*>(&trans[cl * 136 + rl]) = v;
      }
    }
    __syncthreads();
    #pragma unroll
    for (int s = 0; s < BM * BN / 8 / 256; s++) {
      const int u = s * 256 + tid;
      const int cc = u >> (31 - __builtin_clz(BM / 8));
      const int seg = u & (BM / 8 - 1);
      s16x8 v = *reinterpret_cast<const s16x8*>(&trans[cc * 136 + seg * 8]);
      *reinterpret_cast<s16x8*>(
          &((short*)C)[(size_t)(col0 + cc) * ldc + row0 + seg * 8]) = v;
    }
  }
}

// ---------------------------------------------------------------------------
// fp32 -> bf16 conversion for x, Wq, Wk, Wv + rowsum/out zeroing (one launch).
// ---------------------------------------------------------------------------
#define XU  (N_TOK * DDIM / 8)      // 524288
#define WU  (DDIM * DDIM / 8)       // 131072
#define NCVT ((XU + 3 * WU) / 256)  // 3584 convert blocks
#define NZB  1024                   // out-zero blocks (16MB, for split-K pv)
__global__ __launch_bounds__(256)
void cvt_all(const float* __restrict__ x,  const float* __restrict__ wq,
             const float* __restrict__ wk, const float* __restrict__ wv,
             short* __restrict__ xb, short* __restrict__ wqb,
             short* __restrict__ wkb, short* __restrict__ wvb,
             float* __restrict__ rowsum, float* __restrict__ outz)
{
  if (blockIdx.x >= NCVT) {
    const int zb = blockIdx.x - NCVT;
    float4 z = {0.f, 0.f, 0.f, 0.f};
    if (zb < NZB) {
      float4* p = reinterpret_cast<float4*>(outz) +
                  (size_t)zb * 1024 + threadIdx.x * 4;
      p[0] = z; p[1] = z; p[2] = z; p[3] = z;
    } else {
      float4* p = reinterpret_cast<float4*>(rowsum) + threadIdx.x * 4;
      p[0] = z; p[1] = z; p[2] = z; p[3] = z;
    }
    return;
  }
  int gid = blockIdx.x * 256 + threadIdx.x;
  const float* src; short* dst; int off;
  if (gid < XU)               { src = x;  dst = xb;  off = gid; }
  else if (gid < XU + WU)     { src = wq; dst = wqb; off = gid - XU; }
  else if (gid < XU + 2 * WU) { src = wk; dst = wkb; off = gid - XU - WU; }
  else                        { src = wv; dst = wvb; off = gid - XU - 2 * WU; }
  const float4* g = reinterpret_cast<const float4*>(src) + (size_t)off * 2;
  float4 a = g[0], b = g[1];
  s16x8 o;
  o[0] = f2b(a.x); o[1] = f2b(a.y); o[2] = f2b(a.z); o[3] = f2b(a.w);
  o[4] = f2b(b.x); o[5] = f2b(b.y); o[6] = f2b(b.z); o[7] = f2b(b.w);
  reinterpret_cast<s16x8*>(dst)[off] = o;
}

// ---------------------------------------------------------------------------
// GEMM kernels
// ---------------------------------------------------------------------------
__global__ __launch_bounds__(256)
void k_qkv(const short* __restrict__ xb,
           const short* __restrict__ Wqb, const short* __restrict__ Wkb,
           const short* __restrict__ Wvb,
           const float* __restrict__ bq, const float* __restrict__ bk,
           const float* __restrict__ bv,
           short* __restrict__ Qb, short* __restrict__ Kb, short* __restrict__ Vt)
{
  __shared__ short smem[lds_shorts<128, 128, 64, 3>()];   // 17408 shorts
  int bx = blockIdx.x, by = blockIdx.y;
  xcd_remap(DDIM / 128, bx, by);
  if (blockIdx.z == 0) {
    gemm_core<128, 128, 64, 0>(xb, Wqb, Qb, (float*)bq, smem, DDIM, DDIM, DDIM,
                               1.0f, by * 128, bx * 128);
  } else if (blockIdx.z == 1) {
    gemm_core<128, 128, 64, 0>(xb, Wkb, Kb, (float*)bk, smem, DDIM, DDIM, DDIM,
                               1.0f, by * 128, bx * 128);
  } else {
    gemm_core<128, 128, 64, 3>(xb, Wvb, Vt, (float*)bv, smem, DDIM, DDIM, N_TOK,
                               1.0f, by * 128, bx * 128);
  }
}

// 256x128 score tile: 64 MFMA per BK=64 iter; grid 32x16 = 512 = 2/CU.
__global__ __launch_bounds__(256, 2)
void k_score(const short* __restrict__ Qb, const short* __restrict__ Kb,
             short* __restrict__ SP, float* __restrict__ rowsum)
{
  __shared__ short smem[lds_shorts<256, 128, 64, 1>()];   // 24576 shorts
  int bx = blockIdx.x, by = blockIdx.y;
  xcd_remap16(N_TOK / 128, bx, by);
  gemm_core<256, 128, 64, 1>(Qb, Kb, SP, rowsum, smem, DDIM, DDIM, N_TOK,
                             0.03125f, by * 256, bx * 128);
}

// R15: 128x128 pv tile, BK=64, split-K=2; grid (8,32,2)=512 = 2/CU, 32KB LDS.
__global__ __launch_bounds__(256)
void k_pv(const short* __restrict__ SP, const short* __restrict__ Vt,
          float* __restrict__ out, const float* __restrict__ rowsum)
{
  __shared__ short smem[lds_shorts<128, 128, 64, 4>()];   // 16384 shorts, 32KB
  int bx = blockIdx.x, by = blockIdx.y;
  xcd_remap(DDIM / 128, bx, by);
  const int k0 = blockIdx.z * (N_TOK / 2);
  gemm_core<128, 128, 64, 4>(SP + k0, Vt + k0, out, (float*)rowsum, smem,
                             N_TOK / 2, N_TOK, DDIM, 1.0f, by * 128, bx * 128);
}

// ---------------------------------------------------------------------------
extern "C" void kernel_launch(void* const* d_in, const int* in_sizes, int n_in,
                              void* d_out, int out_size, void* d_ws, size_t ws_size,
                              hipStream_t stream)
{
  const float* x  = (const float*)d_in[0];
  const float* Wq = (const float*)d_in[1];
  const float* bq = (const float*)d_in[2];
  const float* Wk = (const float*)d_in[3];
  const float* bk = (const float*)d_in[4];
  const float* Wv = (const float*)d_in[5];
  const float* bv = (const float*)d_in[6];
  float* out = (float*)d_out;

  char* ws = (char*)d_ws;
  const size_t MB = 1024 * 1024;
  short* Qb  = (short*)(ws + 0 * MB);
  short* Kb  = (short*)(ws + 8 * MB);
  short* Vt  = (short*)(ws + 24 * MB);
  short* SP  = (short*)(ws + 32 * MB);   // 32 MB (32..64MB)
  short* xb  = (short*)(ws + 32 * MB);   // overlaps SP (dead before k_score)
  short* Wqb = (short*)(ws + 40 * MB);
  short* Wkb = (short*)(ws + 42 * MB);
  short* Wvb = (short*)(ws + 44 * MB);
  float* rowsum = (float*)(ws + 64 * MB); // past SP (ws >= 112MB, proven R3)

  dim3 b256(256);

  // fp32 -> bf16 for x and the three W's + zero rowsum and out
  cvt_all<<<dim3(NCVT + NZB + 1), b256, 0, stream>>>(
      x, Wq, Wk, Wv, xb, Wqb, Wkb, Wvb, rowsum, out);

  // Q/K = x @ W^T + b (bf16); V-slice writes Vt transposed directly
  k_qkv<<<dim3(DDIM / 128, N_TOK / 128, 3), b256, 0, stream>>>(
      xb, Wqb, Wkb, Wvb, bq, bk, bv, Qb, Kb, Vt);

  // P = exp(Q @ K^T / 32) (bf16) + rowsum atomics; 256x128 tiles
  k_score<<<dim3(N_TOK / 128, N_TOK / 256), b256, 0, stream>>>(
      Qb, Kb, SP, rowsum);

  // O += (P @ Vt^T) / rowsum (fp32 atomics), 128x128 tiles BK=64, split-K=2
  k_pv<<<dim3(DDIM / 128, N_TOK / 128, 2), b256, 0, stream>>>(
      SP, Vt, out, rowsum);
}

// Round 3
// 207.084 us; speedup vs baseline: 1.1835x; 1.1091x over previous
//
#include <hip/hip_runtime.h>

// N=4096, D=1024 self-attention, all GEMMs NT-form bf16 MFMA (16x16x32), fp32 acc.
// R4: BK=64 + XOR swizzle -> 0 bank conflicts. R5: XCD swizzle. R6: k_pv BK=128.
// R7: softmax fused into k_score/k_pv epilogues. R11: rowsum @ ws+64MB via cvt_all.
// R12: V-transpose fused into k_qkv (MODE 3). R13: k_score 256x128 tile.
// R14 (REVERTED): BK=32 ring pipeline regressed ~30% (thin phases, LDS conflicts).
// R15 (REVERTED): k_pv split-K atomicAdd merge cost +13us (WRITE 2x, line
//   collisions). k_pv back to R13 128x64 BK=128 MODE 2.
// R16: k_score rebuilt as 128x128 BK=64 with counted-vmcnt double-buffer
//   (T3+T4+T5): 2 LDS slots (64KB, 2 blk/CU), grid 32x32=1024. Per tile:
//   ds_read frags -> lgkmcnt(0) -> barrier -> issue stage(t+2, same slot) ->
//   MFMA (setprio 1) -> vmcnt(8) -> barrier. Never vmcnt(0) mid-loop: tile
//   t+2's loads stay in flight across barriers, hidden under MFMA(t)+tile(t+1).
//   Race-free by FIFO induction: slot writes issue only after the read-barrier;
//   reads of t+2 only after exit-barrier of t+1 whose vmcnt(8) proves t+2 landed.
//
// ws layout:
//   Qb bf16[4096,1024] @ 0      Kb @ 8MB     Vt bf16[1024,4096] @ 24MB
//   SP bf16[4096,4096] @ 32MB   (exp'd scores; spans 32..64MB)
//   xb @ 32MB (overlaps SP; dead before k_score), Wqb @ 40MB, Wkb @ 42MB, Wvb @ 44MB
//   rowsum fp32[4096] @ 64MB    (past SP; ws_size >= 112MB proven in R3)

#define N_TOK 4096
#define DDIM  1024

typedef short s16x4 __attribute__((ext_vector_type(4)));
typedef short s16x8 __attribute__((ext_vector_type(8)));
typedef float f32x4 __attribute__((ext_vector_type(4)));

#define VMCNT0() asm volatile("s_waitcnt vmcnt(0)" ::: "memory")
#define VMCNT8() asm volatile("s_waitcnt vmcnt(8)" ::: "memory")
#define LGKMCNT0() asm volatile("s_waitcnt lgkmcnt(0)" ::: "memory")
#define BARRIER() do { asm volatile("" ::: "memory"); \
                       __builtin_amdgcn_s_barrier();  \
                       asm volatile("" ::: "memory"); } while (0)

__device__ inline short f2b(float f) {
  unsigned int u = __float_as_uint(f);
  unsigned int r = (u + 0x7FFFu + ((u >> 16) & 1u)) >> 16;
  return (short)(unsigned short)r;
}

__device__ __forceinline__ void gld_lds16(const short* g, short* l) {
  __builtin_amdgcn_global_load_lds(
      (const __attribute__((address_space(1))) unsigned int*)g,
      (__attribute__((address_space(3))) unsigned int*)l, 16, 0, 0);
}

// XCD-locality remap, GY=32 grids: XCD (L%8) owns a 4-row-tile band.
__device__ __forceinline__ void xcd_remap(int gx, int& bx, int& by) {
  const int L = by * gx + bx;
  const int g = L & 7, h = L >> 3;
  by = g * 4 + (h & 3);
  bx = h >> 2;
}
// GY=16 variant (256-row tiles): XCD owns a 2-row-tile band.
__device__ __forceinline__ void xcd_remap16(int gx, int& bx, int& by) {
  const int L = by * gx + bx;
  const int g = L & 7, h = L >> 3;
  by = g * 2 + (h & 1);
  bx = h >> 1;
}

// ---------------------------------------------------------------------------
// Core NT GEMM tile, bf16 in, fp32 acc, 16x16x32 MFMA. MODE epilogues:
//   0: bf16 store of scale*acc + bias                  (aux = bias)
//   2: fp32 store of acc / rowsum[row]                 (aux = rowsum)
//   3: bf16 TRANSPOSED store of acc + bias: C[col*ldc + row]  (aux = bias)
// Caller provides smem of >= lds_shorts<...>() shorts (static per kernel).
// LDS chunk q of row r at slot q ^ (r & (BK/8-1)) -> conflict-free b128 reads.
// ---------------------------------------------------------------------------
template<int BM, int BN, int BK, int MODE>
constexpr int lds_shorts() {
  return (MODE == 3 && BN * 136 > BM * BK + BN * BK) ? BN * 136
                                                     : BM * BK + BN * BK;
}

template<int BM, int BN, int BK, int MODE>
__device__ __forceinline__ void gemm_core(
    const short* __restrict__ A, const short* __restrict__ B,
    void* __restrict__ C, float* __restrict__ aux, short* smem,
    int K, int ld, int ldc, float scale, int row0, int col0)
{
  constexpr int WM = BM / 2, WN = BN / 2, AI = WM / 16, AJ = WN / 16;
  constexpr int CPR = BK / 8;
  constexpr int MASK = CPR - 1;
  constexpr int CA = BM * CPR / 256;
  constexpr int CB = BN * CPR / 256;
  constexpr int NH = BK / 32;
  short* As = smem;
  short* Bs = smem + BM * BK;

  const int tid  = threadIdx.x;
  const int wave = tid >> 6, lane = tid & 63;
  const int wm = wave >> 1, wn = wave & 1;
  const int quad = lane >> 4, lr = lane & 15;

  f32x4 acc[AI][AJ];
  #pragma unroll
  for (int i = 0; i < AI; i++)
    #pragma unroll
    for (int j = 0; j < AJ; j++) acc[i][j] = {0.f, 0.f, 0.f, 0.f};

  for (int kk = 0; kk < K; kk += BK) {
    __syncthreads();
    #pragma unroll
    for (int c = 0; c < CA; c++) {
      const int id = c * 256 + wave * 64 + lane;
      const int r = id / CPR, slot = id & MASK;
      const int q = slot ^ (r & MASK);
      gld_lds16(A + (size_t)(row0 + r) * ld + kk + q * 8,
                &As[(c * 256 + wave * 64) * 8]);
    }
    #pragma unroll
    for (int c = 0; c < CB; c++) {
      const int id = c * 256 + wave * 64 + lane;
      const int r = id / CPR, slot = id & MASK;
      const int q = slot ^ (r & MASK);
      gld_lds16(B + (size_t)(col0 + r) * ld + kk + q * 8,
                &Bs[(c * 256 + wave * 64) * 8]);
    }
    __syncthreads();

    #pragma unroll
    for (int h = 0; h < NH; h++) {
      s16x8 af[AI], bf[AJ];
      #pragma unroll
      for (int i = 0; i < AI; i++) {
        const int row = wm * WM + i * 16 + lr;
        const int ch = (h * 4 + quad) ^ (row & MASK);
        af[i] = *reinterpret_cast<const s16x8*>(&As[(row * CPR + ch) * 8]);
      }
      #pragma unroll
      for (int j = 0; j < AJ; j++) {
        const int row = wn * WN + j * 16 + lr;
        const int ch = (h * 4 + quad) ^ (row & MASK);
        bf[j] = *reinterpret_cast<const s16x8*>(&Bs[(row * CPR + ch) * 8]);
      }
      #pragma unroll
      for (int i = 0; i < AI; i++)
        #pragma unroll
        for (int j = 0; j < AJ; j++)
          acc[i][j] = __builtin_amdgcn_mfma_f32_16x16x32_bf16(af[i], bf[j], acc[i][j], 0, 0, 0);
    }
  }

  if constexpr (MODE == 0) {
    float bb[AJ];
    #pragma unroll
    for (int j = 0; j < AJ; j++) bb[j] = aux[col0 + wn * WN + j * 16 + lr];
    #pragma unroll
    for (int i = 0; i < AI; i++) {
      const int r0 = row0 + wm * WM + i * 16 + quad * 4;
      #pragma unroll
      for (int j = 0; j < AJ; j++) {
        const int c = col0 + wn * WN + j * 16 + lr;
        #pragma unroll
        for (int r = 0; r < 4; r++)
          ((short*)C)[(size_t)(r0 + r) * ldc + c] = f2b(acc[i][j][r] * scale + bb[j]);
      }
    }
  } else if constexpr (MODE == 2) {
    #pragma unroll
    for (int i = 0; i < AI; i++) {
      const int r0 = row0 + wm * WM + i * 16 + quad * 4;
      float linv[4];
      #pragma unroll
      for (int r = 0; r < 4; r++) linv[r] = 1.0f / aux[r0 + r];
      #pragma unroll
      for (int j = 0; j < AJ; j++) {
        const int c = col0 + wn * WN + j * 16 + lr;
        #pragma unroll
        for (int r = 0; r < 4; r++)
          ((float*)C)[(size_t)(r0 + r) * ldc + c] = acc[i][j][r] * linv[r];
      }
    }
  } else {
    // MODE 3: transposed bf16 store with bias. trans[col][row], stride 136.
    float bb[AJ];
    #pragma unroll
    for (int j = 0; j < AJ; j++) bb[j] = aux[col0 + wn * WN + j * 16 + lr];
    __syncthreads();
    short* trans = smem;      // BN x 136 shorts
    #pragma unroll
    for (int i = 0; i < AI; i++) {
      const int rl = wm * WM + i * 16 + quad * 4;
      #pragma unroll
      for (int j = 0; j < AJ; j++) {
        const int cl = wn * WN + j * 16 + lr;
        s16x4 v;
        #pragma unroll
        for (int r = 0; r < 4; r++) v[r] = f2b(acc[i][j][r] * scale + bb[j]);
        *reinterpret_cast<s16x4*>(&trans[cl * 136 + rl]) = v;
      }
    }
    __syncthreads();
    #pragma unroll
    for (int s = 0; s < BM * BN / 8 / 256; s++) {
      const int u = s * 256 + tid;
      const int cc = u >> (31 - __builtin_clz(BM / 8));
      const int seg = u & (BM / 8 - 1);
      s16x8 v = *reinterpret_cast<const s16x8*>(&trans[cc * 136 + seg * 8]);
      *reinterpret_cast<s16x8*>(
          &((short*)C)[(size_t)(cc + col0) * ldc + row0 + seg * 8]) = v;
    }
  }
}

// ---------------------------------------------------------------------------
// fp32 -> bf16 conversion for x, Wq, Wk, Wv + rowsum zeroing (one launch).
// ---------------------------------------------------------------------------
#define XU  (N_TOK * DDIM / 8)      // 524288
#define WU  (DDIM * DDIM / 8)       // 131072
#define NCVT ((XU + 3 * WU) / 256)  // 3584 convert blocks
__global__ __launch_bounds__(256)
void cvt_all(const float* __restrict__ x,  const float* __restrict__ wq,
             const float* __restrict__ wk, const float* __restrict__ wv,
             short* __restrict__ xb, short* __restrict__ wqb,
             short* __restrict__ wkb, short* __restrict__ wvb,
             float* __restrict__ rowsum)
{
  if (blockIdx.x >= NCVT) {
    float4 z = {0.f, 0.f, 0.f, 0.f};
    float4* p = reinterpret_cast<float4*>(rowsum) + threadIdx.x * 4;
    p[0] = z; p[1] = z; p[2] = z; p[3] = z;
    return;
  }
  int gid = blockIdx.x * 256 + threadIdx.x;
  const float* src; short* dst; int off;
  if (gid < XU)               { src = x;  dst = xb;  off = gid; }
  else if (gid < XU + WU)     { src = wq; dst = wqb; off = gid - XU; }
  else if (gid < XU + 2 * WU) { src = wk; dst = wkb; off = gid - XU - WU; }
  else                        { src = wv; dst = wvb; off = gid - XU - 2 * WU; }
  const float4* g = reinterpret_cast<const float4*>(src) + (size_t)off * 2;
  float4 a = g[0], b = g[1];
  s16x8 o;
  o[0] = f2b(a.x); o[1] = f2b(a.y); o[2] = f2b(a.z); o[3] = f2b(a.w);
  o[4] = f2b(b.x); o[5] = f2b(b.y); o[6] = f2b(b.z); o[7] = f2b(b.w);
  reinterpret_cast<s16x8*>(dst)[off] = o;
}

// ---------------------------------------------------------------------------
// GEMM kernels
// ---------------------------------------------------------------------------
__global__ __launch_bounds__(256)
void k_qkv(const short* __restrict__ xb,
           const short* __restrict__ Wqb, const short* __restrict__ Wkb,
           const short* __restrict__ Wvb,
           const float* __restrict__ bq, const float* __restrict__ bk,
           const float* __restrict__ bv,
           short* __restrict__ Qb, short* __restrict__ Kb, short* __restrict__ Vt)
{
  __shared__ short smem[lds_shorts<128, 128, 64, 3>()];   // 17408 shorts
  int bx = blockIdx.x, by = blockIdx.y;
  xcd_remap(DDIM / 128, bx, by);
  if (blockIdx.z == 0) {
    gemm_core<128, 128, 64, 0>(xb, Wqb, Qb, (float*)bq, smem, DDIM, DDIM, DDIM,
                               1.0f, by * 128, bx * 128);
  } else if (blockIdx.z == 1) {
    gemm_core<128, 128, 64, 0>(xb, Wkb, Kb, (float*)bk, smem, DDIM, DDIM, DDIM,
                               1.0f, by * 128, bx * 128);
  } else {
    gemm_core<128, 128, 64, 3>(xb, Wvb, Vt, (float*)bv, smem, DDIM, DDIM, N_TOK,
                               1.0f, by * 128, bx * 128);
  }
}

// ---------------------------------------------------------------------------
// R16 k_score: 128x128 BK=64 counted-vmcnt double-buffer pipeline.
// Grid 32x32 = 1024 blocks; LDS 2 x 32KB = 64KB -> 2 blk/CU; 8 loads/thr/tile.
// Epilogue: bf16 store of exp(scale*acc) + rowsum atomics.
// ---------------------------------------------------------------------------
__global__ __launch_bounds__(256, 2)
void k_score(const short* __restrict__ Qb, const short* __restrict__ Kb,
             short* __restrict__ SP, float* __restrict__ rowsum)
{
  constexpr int BM = 128, BN = 128, BK = 64;
  constexpr int NT = DDIM / BK;                 // 16 K-tiles
  __shared__ short smem[2][(BM + BN) * BK];     // 2 x 16384 shorts = 64 KiB

  int bx = blockIdx.x, by = blockIdx.y;
  xcd_remap(32, bx, by);                        // 32x32 grid, bijective
  const int row0 = by * BM, col0 = bx * BN;

  const int tid  = threadIdx.x;
  const int wave = tid >> 6, lane = tid & 63;
  const int wm = wave >> 1, wn = wave & 1;      // 2x2 waves, 64x64 out each
  const int quad = lane >> 4, lr = lane & 15;

  auto stage = [&](int t, int sl) {
    #pragma unroll
    for (int c = 0; c < 8; c++) {
      const int id = c * 256 + tid;             // 0..2047
      const int r  = id >> 3;                   // rows 0..255 (A:0-127, B:128-255)
      const int q  = (id & 7) ^ (r & 7);
      const short* src = (r < BM)
          ? Qb + (size_t)(row0 + r) * DDIM + t * BK + q * 8
          : Kb + (size_t)(col0 + r - BM) * DDIM + t * BK + q * 8;
      gld_lds16(src, &smem[sl][(c * 256 + wave * 64) * 8]);
    }
  };

  f32x4 acc[4][4];
  #pragma unroll
  for (int i = 0; i < 4; i++)
    #pragma unroll
    for (int j = 0; j < 4; j++) acc[i][j] = {0.f, 0.f, 0.f, 0.f};

  // prologue: tiles 0,1 -> slots 0,1; wait tile 0 (8 of 16 loads may remain).
  stage(0, 0);
  stage(1, 1);
  VMCNT8();
  BARRIER();

  for (int t = 0; t < NT; t++) {
    const int sl = t & 1;
    const short* As = smem[sl];
    const short* Bs = smem[sl] + BM * BK;

    // read ALL fragments of tile t to registers (16 x ds_read_b128)
    s16x8 af[2][4], bf[2][4];
    #pragma unroll
    for (int h = 0; h < 2; h++) {
      #pragma unroll
      for (int i = 0; i < 4; i++) {
        const int row = wm * 64 + i * 16 + lr;
        const int ch = (h * 4 + quad) ^ (row & 7);
        af[h][i] = *reinterpret_cast<const s16x8*>(&As[(row * 8 + ch) * 8]);
      }
      #pragma unroll
      for (int j = 0; j < 4; j++) {
        const int row = wn * 64 + j * 16 + lr;
        const int ch = (h * 4 + quad) ^ (row & 7);
        bf[h][j] = *reinterpret_cast<const s16x8*>(&Bs[(row * 8 + ch) * 8]);
      }
    }
    LGKMCNT0();                                  // reads complete
    __builtin_amdgcn_sched_barrier(0);           // rule #18 fence
    BARRIER();                                   // slot sl reusable block-wide

    const bool pf = (t + 2) < NT;
    if (pf) stage(t + 2, sl);                    // issue into just-freed slot

    __builtin_amdgcn_s_setprio(1);
    #pragma unroll
    for (int h = 0; h < 2; h++)
      #pragma unroll
      for (int i = 0; i < 4; i++)
        #pragma unroll
        for (int j = 0; j < 4; j++)
          acc[i][j] = __builtin_amdgcn_mfma_f32_16x16x32_bf16(
              af[h][i], bf[h][j], acc[i][j], 0, 0, 0);
    __builtin_amdgcn_s_setprio(0);

    // drain to tile t+1 only; t+2's 8 loads stay in flight across the barrier.
    if (pf) { VMCNT8(); } else { VMCNT0(); }
    BARRIER();
  }

  // epilogue: P = exp(scale*acc), bf16 store + rowsum atomics (as R13 MODE 1)
  constexpr float scale = 0.03125f;
  #pragma unroll
  for (int i = 0; i < 4; i++) {
    const int r0 = row0 + wm * 64 + i * 16 + quad * 4;
    float ex[4][4];
    #pragma unroll
    for (int j = 0; j < 4; j++) {
      const int c = col0 + wn * 64 + j * 16 + lr;
      #pragma unroll
      for (int r = 0; r < 4; r++) {
        ex[j][r] = __expf(acc[i][j][r] * scale);
        SP[(size_t)(r0 + r) * N_TOK + c] = f2b(ex[j][r]);
      }
    }
    #pragma unroll
    for (int r = 0; r < 4; r++) {
      float s = 0.f;
      #pragma unroll
      for (int j = 0; j < 4; j++) s += ex[j][r];
      s += __shfl_xor(s, 1, 64);
      s += __shfl_xor(s, 2, 64);
      s += __shfl_xor(s, 4, 64);
      s += __shfl_xor(s, 8, 64);
      if (lr == 0) atomicAdd(&rowsum[r0 + r], s);
    }
  }
}

// R13 k_pv: 128x64 tile, BK=128; grid (16,32)=512 = 2/CU, 48KB LDS.
__global__ __launch_bounds__(256)
void k_pv(const short* __restrict__ SP, const short* __restrict__ Vt,
          float* __restrict__ out, const float* __restrict__ rowsum)
{
  __shared__ short smem[lds_shorts<128, 64, 128, 2>()];   // 24576 shorts
  int bx = blockIdx.x, by = blockIdx.y;
  xcd_remap(DDIM / 64, bx, by);
  gemm_core<128, 64, 128, 2>(SP, Vt, out, (float*)rowsum, smem, N_TOK, N_TOK,
                             DDIM, 1.0f, by * 128, bx * 64);
}

// ---------------------------------------------------------------------------
extern "C" void kernel_launch(void* const* d_in, const int* in_sizes, int n_in,
                              void* d_out, int out_size, void* d_ws, size_t ws_size,
                              hipStream_t stream)
{
  const float* x  = (const float*)d_in[0];
  const float* Wq = (const float*)d_in[1];
  const float* bq = (const float*)d_in[2];
  const float* Wk = (const float*)d_in[3];
  const float* bk = (const float*)d_in[4];
  const float* Wv = (const float*)d_in[5];
  const float* bv = (const float*)d_in[6];
  float* out = (float*)d_out;

  char* ws = (char*)d_ws;
  const size_t MB = 1024 * 1024;
  short* Qb  = (short*)(ws + 0 * MB);
  short* Kb  = (short*)(ws + 8 * MB);
  short* Vt  = (short*)(ws + 24 * MB);
  short* SP  = (short*)(ws + 32 * MB);   // 32 MB (32..64MB)
  short* xb  = (short*)(ws + 32 * MB);   // overlaps SP (dead before k_score)
  short* Wqb = (short*)(ws + 40 * MB);
  short* Wkb = (short*)(ws + 42 * MB);
  short* Wvb = (short*)(ws + 44 * MB);
  float* rowsum = (float*)(ws + 64 * MB); // past SP (ws >= 112MB, proven R3)

  dim3 b256(256);

  // fp32 -> bf16 for x and the three W's + zero rowsum (one extra block)
  cvt_all<<<dim3(NCVT + 1), b256, 0, stream>>>(
      x, Wq, Wk, Wv, xb, Wqb, Wkb, Wvb, rowsum);

  // Q/K = x @ W^T + b (bf16); V-slice writes Vt transposed directly
  k_qkv<<<dim3(DDIM / 128, N_TOK / 128, 3), b256, 0, stream>>>(
      xb, Wqb, Wkb, Wvb, bq, bk, bv, Qb, Kb, Vt);

  // P = exp(Q @ K^T / 32) (bf16) + rowsum atomics; dbuf-pipelined 128x128
  k_score<<<dim3(32, 32), b256, 0, stream>>>(Qb, Kb, SP, rowsum);

  // O = (P @ Vt^T) / rowsum  (fp32 out), 128x64 tiles, BK=128
  k_pv<<<dim3(DDIM / 64, N_TOK / 128), b256, 0, stream>>>(
      SP, Vt, out, rowsum);
}

// Round 4
// 199.953 us; speedup vs baseline: 1.2257x; 1.0357x over previous
//
#include <hip/hip_runtime.h>

// N=4096, D=1024 self-attention, all GEMMs NT-form bf16 MFMA (16x16x32), fp32 acc.
// R4: BK=64 + XOR swizzle -> 0 bank conflicts. R5: XCD swizzle. R6: k_pv BK=128.
// R7: softmax fused into k_score/k_pv epilogues. R11: rowsum @ ws+64MB via cvt_all.
// R12: V-transpose fused into k_qkv (MODE 3). R13: k_score 256x128 tile.
// R14 (REVERTED): BK=32 ring pipeline regressed ~30% (thin phases, LDS conflicts).
// R15 (REVERTED): k_pv split-K atomicAdd merge cost +13us.
// R16 (WIN, 213->207): k_score 128x128 BK=64 counted-vmcnt double-buffer
//   (T3+T4+T5): ds_read frags -> lgkmcnt(0) -> barrier -> stage(t+2, same
//   slot) -> MFMA(setprio 1) -> vmcnt(8) -> barrier. Never vmcnt(0) mid-loop.
// R17: same pipeline ported to k_pv (tile 128x64 kept from R13, BK 128->64
//   for dbuf: 2 x 24KB LDS = 48KB -> 2 blk/CU; 6 loads/thr/tile, vmcnt(6)).
//
// ws layout:
//   Qb bf16[4096,1024] @ 0      Kb @ 8MB     Vt bf16[1024,4096] @ 24MB
//   SP bf16[4096,4096] @ 32MB   (exp'd scores; spans 32..64MB)
//   xb @ 32MB (overlaps SP; dead before k_score), Wqb @ 40MB, Wkb @ 42MB, Wvb @ 44MB
//   rowsum fp32[4096] @ 64MB    (past SP; ws_size >= 112MB proven in R3)

#define N_TOK 4096
#define DDIM  1024

typedef short s16x4 __attribute__((ext_vector_type(4)));
typedef short s16x8 __attribute__((ext_vector_type(8)));
typedef float f32x4 __attribute__((ext_vector_type(4)));

#define VMCNT0() asm volatile("s_waitcnt vmcnt(0)" ::: "memory")
#define VMCNT6() asm volatile("s_waitcnt vmcnt(6)" ::: "memory")
#define VMCNT8() asm volatile("s_waitcnt vmcnt(8)" ::: "memory")
#define LGKMCNT0() asm volatile("s_waitcnt lgkmcnt(0)" ::: "memory")
#define BARRIER() do { asm volatile("" ::: "memory"); \
                       __builtin_amdgcn_s_barrier();  \
                       asm volatile("" ::: "memory"); } while (0)

__device__ inline short f2b(float f) {
  unsigned int u = __float_as_uint(f);
  unsigned int r = (u + 0x7FFFu + ((u >> 16) & 1u)) >> 16;
  return (short)(unsigned short)r;
}

__device__ __forceinline__ void gld_lds16(const short* g, short* l) {
  __builtin_amdgcn_global_load_lds(
      (const __attribute__((address_space(1))) unsigned int*)g,
      (__attribute__((address_space(3))) unsigned int*)l, 16, 0, 0);
}

// XCD-locality remap, GY=32 grids: XCD (L%8) owns a 4-row-tile band.
__device__ __forceinline__ void xcd_remap(int gx, int& bx, int& by) {
  const int L = by * gx + bx;
  const int g = L & 7, h = L >> 3;
  by = g * 4 + (h & 3);
  bx = h >> 2;
}
// GY=16 variant (256-row tiles): XCD owns a 2-row-tile band.
__device__ __forceinline__ void xcd_remap16(int gx, int& bx, int& by) {
  const int L = by * gx + bx;
  const int g = L & 7, h = L >> 3;
  by = g * 2 + (h & 1);
  bx = h >> 1;
}

// ---------------------------------------------------------------------------
// Core NT GEMM tile (legacy 2-phase, used by k_qkv). MODE epilogues:
//   0: bf16 store of scale*acc + bias                  (aux = bias)
//   3: bf16 TRANSPOSED store of acc + bias: C[col*ldc + row]  (aux = bias)
// LDS chunk q of row r at slot q ^ (r & (BK/8-1)) -> conflict-free b128 reads.
// ---------------------------------------------------------------------------
template<int BM, int BN, int BK, int MODE>
constexpr int lds_shorts() {
  return (MODE == 3 && BN * 136 > BM * BK + BN * BK) ? BN * 136
                                                     : BM * BK + BN * BK;
}

template<int BM, int BN, int BK, int MODE>
__device__ __forceinline__ void gemm_core(
    const short* __restrict__ A, const short* __restrict__ B,
    void* __restrict__ C, float* __restrict__ aux, short* smem,
    int K, int ld, int ldc, float scale, int row0, int col0)
{
  constexpr int WM = BM / 2, WN = BN / 2, AI = WM / 16, AJ = WN / 16;
  constexpr int CPR = BK / 8;
  constexpr int MASK = CPR - 1;
  constexpr int CA = BM * CPR / 256;
  constexpr int CB = BN * CPR / 256;
  constexpr int NH = BK / 32;
  short* As = smem;
  short* Bs = smem + BM * BK;

  const int tid  = threadIdx.x;
  const int wave = tid >> 6, lane = tid & 63;
  const int wm = wave >> 1, wn = wave & 1;
  const int quad = lane >> 4, lr = lane & 15;

  f32x4 acc[AI][AJ];
  #pragma unroll
  for (int i = 0; i < AI; i++)
    #pragma unroll
    for (int j = 0; j < AJ; j++) acc[i][j] = {0.f, 0.f, 0.f, 0.f};

  for (int kk = 0; kk < K; kk += BK) {
    __syncthreads();
    #pragma unroll
    for (int c = 0; c < CA; c++) {
      const int id = c * 256 + wave * 64 + lane;
      const int r = id / CPR, slot = id & MASK;
      const int q = slot ^ (r & MASK);
      gld_lds16(A + (size_t)(row0 + r) * ld + kk + q * 8,
                &As[(c * 256 + wave * 64) * 8]);
    }
    #pragma unroll
    for (int c = 0; c < CB; c++) {
      const int id = c * 256 + wave * 64 + lane;
      const int r = id / CPR, slot = id & MASK;
      const int q = slot ^ (r & MASK);
      gld_lds16(B + (size_t)(col0 + r) * ld + kk + q * 8,
                &Bs[(c * 256 + wave * 64) * 8]);
    }
    __syncthreads();

    #pragma unroll
    for (int h = 0; h < NH; h++) {
      s16x8 af[AI], bf[AJ];
      #pragma unroll
      for (int i = 0; i < AI; i++) {
        const int row = wm * WM + i * 16 + lr;
        const int ch = (h * 4 + quad) ^ (row & MASK);
        af[i] = *reinterpret_cast<const s16x8*>(&As[(row * CPR + ch) * 8]);
      }
      #pragma unroll
      for (int j = 0; j < AJ; j++) {
        const int row = wn * WN + j * 16 + lr;
        const int ch = (h * 4 + quad) ^ (row & MASK);
        bf[j] = *reinterpret_cast<const s16x8*>(&Bs[(row * CPR + ch) * 8]);
      }
      #pragma unroll
      for (int i = 0; i < AI; i++)
        #pragma unroll
        for (int j = 0; j < AJ; j++)
          acc[i][j] = __builtin_amdgcn_mfma_f32_16x16x32_bf16(af[i], bf[j], acc[i][j], 0, 0, 0);
    }
  }

  if constexpr (MODE == 0) {
    float bb[AJ];
    #pragma unroll
    for (int j = 0; j < AJ; j++) bb[j] = aux[col0 + wn * WN + j * 16 + lr];
    #pragma unroll
    for (int i = 0; i < AI; i++) {
      const int r0 = row0 + wm * WM + i * 16 + quad * 4;
      #pragma unroll
      for (int j = 0; j < AJ; j++) {
        const int c = col0 + wn * WN + j * 16 + lr;
        #pragma unroll
        for (int r = 0; r < 4; r++)
          ((short*)C)[(size_t)(r0 + r) * ldc + c] = f2b(acc[i][j][r] * scale + bb[j]);
      }
    }
  } else {
    // MODE 3: transposed bf16 store with bias. trans[col][row], stride 136.
    float bb[AJ];
    #pragma unroll
    for (int j = 0; j < AJ; j++) bb[j] = aux[col0 + wn * WN + j * 16 + lr];
    __syncthreads();
    short* trans = smem;      // BN x 136 shorts
    #pragma unroll
    for (int i = 0; i < AI; i++) {
      const int rl = wm * WM + i * 16 + quad * 4;
      #pragma unroll
      for (int j = 0; j < AJ; j++) {
        const int cl = wn * WN + j * 16 + lr;
        s16x4 v;
        #pragma unroll
        for (int r = 0; r < 4; r++) v[r] = f2b(acc[i][j][r] * scale + bb[j]);
        *reinterpret_cast<s16x4*>(&trans[cl * 136 + rl]) = v;
      }
    }
    __syncthreads();
    #pragma unroll
    for (int s = 0; s < BM * BN / 8 / 256; s++) {
      const int u = s * 256 + tid;
      const int cc = u >> (31 - __builtin_clz(BM / 8));
      const int seg = u & (BM / 8 - 1);
      s16x8 v = *reinterpret_cast<const s16x8*>(&trans[cc * 136 + seg * 8]);
      *reinterpret_cast<s16x8*>(
          &((short*)C)[(size_t)(cc + col0) * ldc + row0 + seg * 8]) = v;
    }
  }
}

// ---------------------------------------------------------------------------
// fp32 -> bf16 conversion for x, Wq, Wk, Wv + rowsum zeroing (one launch).
// ---------------------------------------------------------------------------
#define XU  (N_TOK * DDIM / 8)      // 524288
#define WU  (DDIM * DDIM / 8)       // 131072
#define NCVT ((XU + 3 * WU) / 256)  // 3584 convert blocks
__global__ __launch_bounds__(256)
void cvt_all(const float* __restrict__ x,  const float* __restrict__ wq,
             const float* __restrict__ wk, const float* __restrict__ wv,
             short* __restrict__ xb, short* __restrict__ wqb,
             short* __restrict__ wkb, short* __restrict__ wvb,
             float* __restrict__ rowsum)
{
  if (blockIdx.x >= NCVT) {
    float4 z = {0.f, 0.f, 0.f, 0.f};
    float4* p = reinterpret_cast<float4*>(rowsum) + threadIdx.x * 4;
    p[0] = z; p[1] = z; p[2] = z; p[3] = z;
    return;
  }
  int gid = blockIdx.x * 256 + threadIdx.x;
  const float* src; short* dst; int off;
  if (gid < XU)               { src = x;  dst = xb;  off = gid; }
  else if (gid < XU + WU)     { src = wq; dst = wqb; off = gid - XU; }
  else if (gid < XU + 2 * WU) { src = wk; dst = wkb; off = gid - XU - WU; }
  else                        { src = wv; dst = wvb; off = gid - XU - 2 * WU; }
  const float4* g = reinterpret_cast<const float4*>(src) + (size_t)off * 2;
  float4 a = g[0], b = g[1];
  s16x8 o;
  o[0] = f2b(a.x); o[1] = f2b(a.y); o[2] = f2b(a.z); o[3] = f2b(a.w);
  o[4] = f2b(b.x); o[5] = f2b(b.y); o[6] = f2b(b.z); o[7] = f2b(b.w);
  reinterpret_cast<s16x8*>(dst)[off] = o;
}

// ---------------------------------------------------------------------------
// GEMM kernels
// ---------------------------------------------------------------------------
__global__ __launch_bounds__(256)
void k_qkv(const short* __restrict__ xb,
           const short* __restrict__ Wqb, const short* __restrict__ Wkb,
           const short* __restrict__ Wvb,
           const float* __restrict__ bq, const float* __restrict__ bk,
           const float* __restrict__ bv,
           short* __restrict__ Qb, short* __restrict__ Kb, short* __restrict__ Vt)
{
  __shared__ short smem[lds_shorts<128, 128, 64, 3>()];   // 17408 shorts
  int bx = blockIdx.x, by = blockIdx.y;
  xcd_remap(DDIM / 128, bx, by);
  if (blockIdx.z == 0) {
    gemm_core<128, 128, 64, 0>(xb, Wqb, Qb, (float*)bq, smem, DDIM, DDIM, DDIM,
                               1.0f, by * 128, bx * 128);
  } else if (blockIdx.z == 1) {
    gemm_core<128, 128, 64, 0>(xb, Wkb, Kb, (float*)bk, smem, DDIM, DDIM, DDIM,
                               1.0f, by * 128, bx * 128);
  } else {
    gemm_core<128, 128, 64, 3>(xb, Wvb, Vt, (float*)bv, smem, DDIM, DDIM, N_TOK,
                               1.0f, by * 128, bx * 128);
  }
}

// ---------------------------------------------------------------------------
// R16 k_score: 128x128 BK=64 counted-vmcnt double-buffer pipeline.
// Grid 32x32 = 1024 blocks; LDS 2 x 32KB = 64KB -> 2 blk/CU; 8 loads/thr/tile.
// ---------------------------------------------------------------------------
__global__ __launch_bounds__(256, 2)
void k_score(const short* __restrict__ Qb, const short* __restrict__ Kb,
             short* __restrict__ SP, float* __restrict__ rowsum)
{
  constexpr int BM = 128, BN = 128, BK = 64;
  constexpr int NT = DDIM / BK;                 // 16 K-tiles
  __shared__ short smem[2][(BM + BN) * BK];     // 2 x 16384 shorts = 64 KiB

  int bx = blockIdx.x, by = blockIdx.y;
  xcd_remap(32, bx, by);                        // 32x32 grid, bijective
  const int row0 = by * BM, col0 = bx * BN;

  const int tid  = threadIdx.x;
  const int wave = tid >> 6, lane = tid & 63;
  const int wm = wave >> 1, wn = wave & 1;      // 2x2 waves, 64x64 out each
  const int quad = lane >> 4, lr = lane & 15;

  auto stage = [&](int t, int sl) {
    #pragma unroll
    for (int c = 0; c < 8; c++) {
      const int id = c * 256 + tid;             // 0..2047
      const int r  = id >> 3;                   // rows 0..255 (A:0-127, B:128-255)
      const int q  = (id & 7) ^ (r & 7);
      const short* src = (r < BM)
          ? Qb + (size_t)(row0 + r) * DDIM + t * BK + q * 8
          : Kb + (size_t)(col0 + r - BM) * DDIM + t * BK + q * 8;
      gld_lds16(src, &smem[sl][(c * 256 + wave * 64) * 8]);
    }
  };

  f32x4 acc[4][4];
  #pragma unroll
  for (int i = 0; i < 4; i++)
    #pragma unroll
    for (int j = 0; j < 4; j++) acc[i][j] = {0.f, 0.f, 0.f, 0.f};

  stage(0, 0);
  stage(1, 1);
  VMCNT8();
  BARRIER();

  for (int t = 0; t < NT; t++) {
    const int sl = t & 1;
    const short* As = smem[sl];
    const short* Bs = smem[sl] + BM * BK;

    s16x8 af[2][4], bf[2][4];
    #pragma unroll
    for (int h = 0; h < 2; h++) {
      #pragma unroll
      for (int i = 0; i < 4; i++) {
        const int row = wm * 64 + i * 16 + lr;
        const int ch = (h * 4 + quad) ^ (row & 7);
        af[h][i] = *reinterpret_cast<const s16x8*>(&As[(row * 8 + ch) * 8]);
      }
      #pragma unroll
      for (int j = 0; j < 4; j++) {
        const int row = wn * 64 + j * 16 + lr;
        const int ch = (h * 4 + quad) ^ (row & 7);
        bf[h][j] = *reinterpret_cast<const s16x8*>(&Bs[(row * 8 + ch) * 8]);
      }
    }
    LGKMCNT0();
    __builtin_amdgcn_sched_barrier(0);
    BARRIER();                                   // slot sl reusable block-wide

    const bool pf = (t + 2) < NT;
    if (pf) stage(t + 2, sl);

    __builtin_amdgcn_s_setprio(1);
    #pragma unroll
    for (int h = 0; h < 2; h++)
      #pragma unroll
      for (int i = 0; i < 4; i++)
        #pragma unroll
        for (int j = 0; j < 4; j++)
          acc[i][j] = __builtin_amdgcn_mfma_f32_16x16x32_bf16(
              af[h][i], bf[h][j], acc[i][j], 0, 0, 0);
    __builtin_amdgcn_s_setprio(0);

    if (pf) { VMCNT8(); } else { VMCNT0(); }
    BARRIER();
  }

  constexpr float scale = 0.03125f;
  #pragma unroll
  for (int i = 0; i < 4; i++) {
    const int r0 = row0 + wm * 64 + i * 16 + quad * 4;
    float ex[4][4];
    #pragma unroll
    for (int j = 0; j < 4; j++) {
      const int c = col0 + wn * 64 + j * 16 + lr;
      #pragma unroll
      for (int r = 0; r < 4; r++) {
        ex[j][r] = __expf(acc[i][j][r] * scale);
        SP[(size_t)(r0 + r) * N_TOK + c] = f2b(ex[j][r]);
      }
    }
    #pragma unroll
    for (int r = 0; r < 4; r++) {
      float s = 0.f;
      #pragma unroll
      for (int j = 0; j < 4; j++) s += ex[j][r];
      s += __shfl_xor(s, 1, 64);
      s += __shfl_xor(s, 2, 64);
      s += __shfl_xor(s, 4, 64);
      s += __shfl_xor(s, 8, 64);
      if (lr == 0) atomicAdd(&rowsum[r0 + r], s);
    }
  }
}

// ---------------------------------------------------------------------------
// R17 k_pv: 128x64 tile, BK=64, counted-vmcnt double-buffer (R16 schedule).
// Grid (16,32)=512 = 2 blk/CU; LDS 2 x 24KB = 48KB; 6 loads/thr/tile, vmcnt(6).
// Epilogue: fp32 store of acc / rowsum[row].
// ---------------------------------------------------------------------------
__global__ __launch_bounds__(256, 2)
void k_pv(const short* __restrict__ SP, const short* __restrict__ Vt,
          float* __restrict__ out, const float* __restrict__ rowsum)
{
  constexpr int BM = 128, BN = 64, BK = 64;
  constexpr int NT = N_TOK / BK;                // 64 K-tiles
  __shared__ short smem[2][(BM + BN) * BK];     // 2 x 12288 shorts = 48 KiB

  int bx = blockIdx.x, by = blockIdx.y;
  xcd_remap(DDIM / 64, bx, by);
  const int row0 = by * BM, col0 = bx * BN;

  const int tid  = threadIdx.x;
  const int wave = tid >> 6, lane = tid & 63;
  const int wm = wave >> 1, wn = wave & 1;      // 2x2 waves, 64x32 out each
  const int quad = lane >> 4, lr = lane & 15;

  auto stage = [&](int t, int sl) {
    #pragma unroll
    for (int c = 0; c < 6; c++) {
      const int id = c * 256 + tid;             // 0..1535
      const int r  = id >> 3;                   // rows 0..191 (A:0-127, B:128-191)
      const int q  = (id & 7) ^ (r & 7);
      const short* src = (r < BM)
          ? SP + (size_t)(row0 + r) * N_TOK + t * BK + q * 8
          : Vt + (size_t)(col0 + r - BM) * N_TOK + t * BK + q * 8;
      gld_lds16(src, &smem[sl][(c * 256 + wave * 64) * 8]);
    }
  };

  f32x4 acc[4][2];
  #pragma unroll
  for (int i = 0; i < 4; i++)
    #pragma unroll
    for (int j = 0; j < 2; j++) acc[i][j] = {0.f, 0.f, 0.f, 0.f};

  stage(0, 0);
  stage(1, 1);
  VMCNT6();
  BARRIER();

  for (int t = 0; t < NT; t++) {
    const int sl = t & 1;
    const short* As = smem[sl];
    const short* Bs = smem[sl] + BM * BK;

    s16x8 af[2][4], bf[2][2];
    #pragma unroll
    for (int h = 0; h < 2; h++) {
      #pragma unroll
      for (int i = 0; i < 4; i++) {
        const int row = wm * 64 + i * 16 + lr;
        const int ch = (h * 4 + quad) ^ (row & 7);
        af[h][i] = *reinterpret_cast<const s16x8*>(&As[(row * 8 + ch) * 8]);
      }
      #pragma unroll
      for (int j = 0; j < 2; j++) {
        const int row = wn * 32 + j * 16 + lr;
        const int ch = (h * 4 + quad) ^ (row & 7);
        bf[h][j] = *reinterpret_cast<const s16x8*>(&Bs[(row * 8 + ch) * 8]);
      }
    }
    LGKMCNT0();
    __builtin_amdgcn_sched_barrier(0);
    BARRIER();                                   // slot sl reusable block-wide

    const bool pf = (t + 2) < NT;
    if (pf) stage(t + 2, sl);

    __builtin_amdgcn_s_setprio(1);
    #pragma unroll
    for (int h = 0; h < 2; h++)
      #pragma unroll
      for (int i = 0; i < 4; i++)
        #pragma unroll
        for (int j = 0; j < 2; j++)
          acc[i][j] = __builtin_amdgcn_mfma_f32_16x16x32_bf16(
              af[h][i], bf[h][j], acc[i][j], 0, 0, 0);
    __builtin_amdgcn_s_setprio(0);

    if (pf) { VMCNT6(); } else { VMCNT0(); }
    BARRIER();
  }

  // epilogue: O = acc / rowsum[row], fp32 coalesced store
  #pragma unroll
  for (int i = 0; i < 4; i++) {
    const int r0 = row0 + wm * 64 + i * 16 + quad * 4;
    float linv[4];
    #pragma unroll
    for (int r = 0; r < 4; r++) linv[r] = 1.0f / rowsum[r0 + r];
    #pragma unroll
    for (int j = 0; j < 2; j++) {
      const int c = col0 + wn * 32 + j * 16 + lr;
      #pragma unroll
      for (int r = 0; r < 4; r++)
        out[(size_t)(r0 + r) * DDIM + c] = acc[i][j][r] * linv[r];
    }
  }
}

// ---------------------------------------------------------------------------
extern "C" void kernel_launch(void* const* d_in, const int* in_sizes, int n_in,
                              void* d_out, int out_size, void* d_ws, size_t ws_size,
                              hipStream_t stream)
{
  const float* x  = (const float*)d_in[0];
  const float* Wq = (const float*)d_in[1];
  const float* bq = (const float*)d_in[2];
  const float* Wk = (const float*)d_in[3];
  const float* bk = (const float*)d_in[4];
  const float* Wv = (const float*)d_in[5];
  const float* bv = (const float*)d_in[6];
  float* out = (float*)d_out;

  char* ws = (char*)d_ws;
  const size_t MB = 1024 * 1024;
  short* Qb  = (short*)(ws + 0 * MB);
  short* Kb  = (short*)(ws + 8 * MB);
  short* Vt  = (short*)(ws + 24 * MB);
  short* SP  = (short*)(ws + 32 * MB);   // 32 MB (32..64MB)
  short* xb  = (short*)(ws + 32 * MB);   // overlaps SP (dead before k_score)
  short* Wqb = (short*)(ws + 40 * MB);
  short* Wkb = (short*)(ws + 42 * MB);
  short* Wvb = (short*)(ws + 44 * MB);
  float* rowsum = (float*)(ws + 64 * MB); // past SP (ws >= 112MB, proven R3)

  dim3 b256(256);

  // fp32 -> bf16 for x and the three W's + zero rowsum (one extra block)
  cvt_all<<<dim3(NCVT + 1), b256, 0, stream>>>(
      x, Wq, Wk, Wv, xb, Wqb, Wkb, Wvb, rowsum);

  // Q/K = x @ W^T + b (bf16); V-slice writes Vt transposed directly
  k_qkv<<<dim3(DDIM / 128, N_TOK / 128, 3), b256, 0, stream>>>(
      xb, Wqb, Wkb, Wvb, bq, bk, bv, Qb, Kb, Vt);

  // P = exp(Q @ K^T / 32) (bf16) + rowsum atomics; dbuf-pipelined 128x128
  k_score<<<dim3(32, 32), b256, 0, stream>>>(Qb, Kb, SP, rowsum);

  // O = (P @ Vt^T) / rowsum (fp32 out), dbuf-pipelined 128x64 BK=64
  k_pv<<<dim3(DDIM / 64, N_TOK / 128), b256, 0, stream>>>(
      SP, Vt, out, rowsum);
}

// Round 5
// 197.748 us; speedup vs baseline: 1.2394x; 1.0112x over previous
//
#include <hip/hip_runtime.h>

// N=4096, D=1024 self-attention, all GEMMs NT-form bf16 MFMA (16x16x32), fp32 acc.
// R4: BK=64 + XOR swizzle -> 0 bank conflicts. R5: XCD swizzle. R6: k_pv BK=128.
// R7: softmax fused into k_score/k_pv epilogues. R11: rowsum @ ws+64MB via cvt_all.
// R12: V-transpose fused into k_qkv (MODE 3). R13: k_score 256x128 tile.
// R14 (REVERTED): BK=32 ring pipeline regressed ~30%. R15 (REVERTED): split-K atomics.
// R16 (WIN, 213->207): k_score 128x128 BK=64 counted-vmcnt double-buffer
//   (T3+T4+T5): ds_read frags -> lgkmcnt(0) -> barrier -> stage(t+2, same
//   slot) -> MFMA(setprio 1) -> vmcnt(8) -> barrier. Never vmcnt(0) mid-loop.
// R17 (WIN, 207->200): same pipeline on k_pv (128x64, BK=64, vmcnt(6)).
// R18: same pipeline on k_qkv (128x128, BK=64, vmcnt(8)) -- third application
//   of the twice-proven template. MODE 0 (bf16+bias) and MODE 3 (transposed
//   store) epilogues kept; MODE 3 trans buffer reuses slot-0 LDS after the
//   tail vmcnt(0)+barrier drains all reads.
//
// ws layout:
//   Qb bf16[4096,1024] @ 0      Kb @ 8MB     Vt bf16[1024,4096] @ 24MB
//   SP bf16[4096,4096] @ 32MB   (exp'd scores; spans 32..64MB)
//   xb @ 32MB (overlaps SP; dead before k_score), Wqb @ 40MB, Wkb @ 42MB, Wvb @ 44MB
//   rowsum fp32[4096] @ 64MB    (past SP; ws_size >= 112MB proven in R3)

#define N_TOK 4096
#define DDIM  1024

typedef short s16x4 __attribute__((ext_vector_type(4)));
typedef short s16x8 __attribute__((ext_vector_type(8)));
typedef float f32x4 __attribute__((ext_vector_type(4)));

#define VMCNT0() asm volatile("s_waitcnt vmcnt(0)" ::: "memory")
#define VMCNT6() asm volatile("s_waitcnt vmcnt(6)" ::: "memory")
#define VMCNT8() asm volatile("s_waitcnt vmcnt(8)" ::: "memory")
#define LGKMCNT0() asm volatile("s_waitcnt lgkmcnt(0)" ::: "memory")
#define BARRIER() do { asm volatile("" ::: "memory"); \
                       __builtin_amdgcn_s_barrier();  \
                       asm volatile("" ::: "memory"); } while (0)

__device__ inline short f2b(float f) {
  unsigned int u = __float_as_uint(f);
  unsigned int r = (u + 0x7FFFu + ((u >> 16) & 1u)) >> 16;
  return (short)(unsigned short)r;
}

__device__ __forceinline__ void gld_lds16(const short* g, short* l) {
  __builtin_amdgcn_global_load_lds(
      (const __attribute__((address_space(1))) unsigned int*)g,
      (__attribute__((address_space(3))) unsigned int*)l, 16, 0, 0);
}

// XCD-locality remap, GY=32 grids: XCD (L%8) owns a 4-row-tile band.
__device__ __forceinline__ void xcd_remap(int gx, int& bx, int& by) {
  const int L = by * gx + bx;
  const int g = L & 7, h = L >> 3;
  by = g * 4 + (h & 3);
  bx = h >> 2;
}

// ---------------------------------------------------------------------------
// R18 pipelined 128x128 BK=64 NT GEMM (R16 schedule). MODE epilogues:
//   0: bf16 store of scale*acc + bias                  (aux = bias)
//   3: bf16 TRANSPOSED store of acc + bias             (aux = bias)
// smem: 2 slots x 16384 shorts (64 KiB). ldA == ldB == ld.
// ---------------------------------------------------------------------------
template<int MODE>
__device__ __forceinline__ void gemm_pipe128(
    const short* __restrict__ A, const short* __restrict__ B,
    void* __restrict__ C, const float* __restrict__ aux,
    short (*smem)[(128 + 128) * 64],
    int K, int ld, int ldc, float scale, int row0, int col0)
{
  constexpr int BM = 128, BN = 128, BK = 64;
  const int NT = K / BK;

  const int tid  = threadIdx.x;
  const int wave = tid >> 6, lane = tid & 63;
  const int wm = wave >> 1, wn = wave & 1;      // 2x2 waves, 64x64 out each
  const int quad = lane >> 4, lr = lane & 15;

  auto stage = [&](int t, int sl) {
    #pragma unroll
    for (int c = 0; c < 8; c++) {
      const int id = c * 256 + tid;             // 0..2047
      const int r  = id >> 3;                   // rows 0..255 (A:0-127, B:128-255)
      const int q  = (id & 7) ^ (r & 7);
      const short* src = (r < BM)
          ? A + (size_t)(row0 + r) * ld + t * BK + q * 8
          : B + (size_t)(col0 + r - BM) * ld + t * BK + q * 8;
      gld_lds16(src, &smem[sl][(c * 256 + wave * 64) * 8]);
    }
  };

  f32x4 acc[4][4];
  #pragma unroll
  for (int i = 0; i < 4; i++)
    #pragma unroll
    for (int j = 0; j < 4; j++) acc[i][j] = {0.f, 0.f, 0.f, 0.f};

  stage(0, 0);
  stage(1, 1);
  VMCNT8();
  BARRIER();

  for (int t = 0; t < NT; t++) {
    const int sl = t & 1;
    const short* As = smem[sl];
    const short* Bs = smem[sl] + BM * BK;

    s16x8 af[2][4], bf[2][4];
    #pragma unroll
    for (int h = 0; h < 2; h++) {
      #pragma unroll
      for (int i = 0; i < 4; i++) {
        const int row = wm * 64 + i * 16 + lr;
        const int ch = (h * 4 + quad) ^ (row & 7);
        af[h][i] = *reinterpret_cast<const s16x8*>(&As[(row * 8 + ch) * 8]);
      }
      #pragma unroll
      for (int j = 0; j < 4; j++) {
        const int row = wn * 64 + j * 16 + lr;
        const int ch = (h * 4 + quad) ^ (row & 7);
        bf[h][j] = *reinterpret_cast<const s16x8*>(&Bs[(row * 8 + ch) * 8]);
      }
    }
    LGKMCNT0();
    __builtin_amdgcn_sched_barrier(0);
    BARRIER();                                   // slot sl reusable block-wide

    const bool pf = (t + 2) < NT;
    if (pf) stage(t + 2, sl);

    __builtin_amdgcn_s_setprio(1);
    #pragma unroll
    for (int h = 0; h < 2; h++)
      #pragma unroll
      for (int i = 0; i < 4; i++)
        #pragma unroll
        for (int j = 0; j < 4; j++)
          acc[i][j] = __builtin_amdgcn_mfma_f32_16x16x32_bf16(
              af[h][i], bf[h][j], acc[i][j], 0, 0, 0);
    __builtin_amdgcn_s_setprio(0);

    if (pf) { VMCNT8(); } else { VMCNT0(); }
    BARRIER();
  }
  // loop exit: all LDS reads drained (tail vmcnt(0)+barrier) -> smem reusable.

  if constexpr (MODE == 0) {
    float bb[4];
    #pragma unroll
    for (int j = 0; j < 4; j++) bb[j] = aux[col0 + wn * 64 + j * 16 + lr];
    #pragma unroll
    for (int i = 0; i < 4; i++) {
      const int r0 = row0 + wm * 64 + i * 16 + quad * 4;
      #pragma unroll
      for (int j = 0; j < 4; j++) {
        const int c = col0 + wn * 64 + j * 16 + lr;
        #pragma unroll
        for (int r = 0; r < 4; r++)
          ((short*)C)[(size_t)(r0 + r) * ldc + c] = f2b(acc[i][j][r] * scale + bb[j]);
      }
    }
  } else {
    // MODE 3: transposed bf16 store with bias. trans[col][row], stride 136.
    float bb[4];
    #pragma unroll
    for (int j = 0; j < 4; j++) bb[j] = aux[col0 + wn * 64 + j * 16 + lr];
    short* trans = &smem[0][0];                  // 128 x 136 shorts = 34816 B
    #pragma unroll
    for (int i = 0; i < 4; i++) {
      const int rl = wm * 64 + i * 16 + quad * 4;
      #pragma unroll
      for (int j = 0; j < 4; j++) {
        const int cl = wn * 64 + j * 16 + lr;
        s16x4 v;
        #pragma unroll
        for (int r = 0; r < 4; r++) v[r] = f2b(acc[i][j][r] * scale + bb[j]);
        *reinterpret_cast<s16x4*>(&trans[cl * 136 + rl]) = v;
      }
    }
    BARRIER();
    #pragma unroll
    for (int s = 0; s < 8; s++) {
      const int u = s * 256 + tid;
      const int cc = u >> 4;                     // column 0..127
      const int seg = u & 15;                    // 16 segs x 8 shorts = 128 rows
      s16x8 v = *reinterpret_cast<const s16x8*>(&trans[cc * 136 + seg * 8]);
      *reinterpret_cast<s16x8*>(
          &((short*)C)[(size_t)(col0 + cc) * ldc + row0 + seg * 8]) = v;
    }
  }
}

// ---------------------------------------------------------------------------
// fp32 -> bf16 conversion for x, Wq, Wk, Wv + rowsum zeroing (one launch).
// ---------------------------------------------------------------------------
#define XU  (N_TOK * DDIM / 8)      // 524288
#define WU  (DDIM * DDIM / 8)       // 131072
#define NCVT ((XU + 3 * WU) / 256)  // 3584 convert blocks
__global__ __launch_bounds__(256)
void cvt_all(const float* __restrict__ x,  const float* __restrict__ wq,
             const float* __restrict__ wk, const float* __restrict__ wv,
             short* __restrict__ xb, short* __restrict__ wqb,
             short* __restrict__ wkb, short* __restrict__ wvb,
             float* __restrict__ rowsum)
{
  if (blockIdx.x >= NCVT) {
    float4 z = {0.f, 0.f, 0.f, 0.f};
    float4* p = reinterpret_cast<float4*>(rowsum) + threadIdx.x * 4;
    p[0] = z; p[1] = z; p[2] = z; p[3] = z;
    return;
  }
  int gid = blockIdx.x * 256 + threadIdx.x;
  const float* src; short* dst; int off;
  if (gid < XU)               { src = x;  dst = xb;  off = gid; }
  else if (gid < XU + WU)     { src = wq; dst = wqb; off = gid - XU; }
  else if (gid < XU + 2 * WU) { src = wk; dst = wkb; off = gid - XU - WU; }
  else                        { src = wv; dst = wvb; off = gid - XU - 2 * WU; }
  const float4* g = reinterpret_cast<const float4*>(src) + (size_t)off * 2;
  float4 a = g[0], b = g[1];
  s16x8 o;
  o[0] = f2b(a.x); o[1] = f2b(a.y); o[2] = f2b(a.z); o[3] = f2b(a.w);
  o[4] = f2b(b.x); o[5] = f2b(b.y); o[6] = f2b(b.z); o[7] = f2b(b.w);
  reinterpret_cast<s16x8*>(dst)[off] = o;
}

// ---------------------------------------------------------------------------
// R18 k_qkv: pipelined 128x128 BK=64; grid (8,32,3); LDS 64KB -> 2 blk/CU.
// ---------------------------------------------------------------------------
__global__ __launch_bounds__(256, 2)
void k_qkv(const short* __restrict__ xb,
           const short* __restrict__ Wqb, const short* __restrict__ Wkb,
           const short* __restrict__ Wvb,
           const float* __restrict__ bq, const float* __restrict__ bk,
           const float* __restrict__ bv,
           short* __restrict__ Qb, short* __restrict__ Kb, short* __restrict__ Vt)
{
  __shared__ short smem[2][(128 + 128) * 64];   // 64 KiB
  int bx = blockIdx.x, by = blockIdx.y;
  xcd_remap(DDIM / 128, bx, by);
  if (blockIdx.z == 0) {
    gemm_pipe128<0>(xb, Wqb, Qb, bq, smem, DDIM, DDIM, DDIM,
                    1.0f, by * 128, bx * 128);
  } else if (blockIdx.z == 1) {
    gemm_pipe128<0>(xb, Wkb, Kb, bk, smem, DDIM, DDIM, DDIM,
                    1.0f, by * 128, bx * 128);
  } else {
    gemm_pipe128<3>(xb, Wvb, Vt, bv, smem, DDIM, DDIM, N_TOK,
                    1.0f, by * 128, bx * 128);
  }
}

// ---------------------------------------------------------------------------
// R16 k_score: 128x128 BK=64 counted-vmcnt double-buffer pipeline.
// Grid 32x32 = 1024 blocks; LDS 2 x 32KB = 64KB -> 2 blk/CU; 8 loads/thr/tile.
// ---------------------------------------------------------------------------
__global__ __launch_bounds__(256, 2)
void k_score(const short* __restrict__ Qb, const short* __restrict__ Kb,
             short* __restrict__ SP, float* __restrict__ rowsum)
{
  constexpr int BM = 128, BN = 128, BK = 64;
  constexpr int NT = DDIM / BK;                 // 16 K-tiles
  __shared__ short smem[2][(BM + BN) * BK];     // 2 x 16384 shorts = 64 KiB

  int bx = blockIdx.x, by = blockIdx.y;
  xcd_remap(32, bx, by);                        // 32x32 grid, bijective
  const int row0 = by * BM, col0 = bx * BN;

  const int tid  = threadIdx.x;
  const int wave = tid >> 6, lane = tid & 63;
  const int wm = wave >> 1, wn = wave & 1;      // 2x2 waves, 64x64 out each
  const int quad = lane >> 4, lr = lane & 15;

  auto stage = [&](int t, int sl) {
    #pragma unroll
    for (int c = 0; c < 8; c++) {
      const int id = c * 256 + tid;             // 0..2047
      const int r  = id >> 3;                   // rows 0..255 (A:0-127, B:128-255)
      const int q  = (id & 7) ^ (r & 7);
      const short* src = (r < BM)
          ? Qb + (size_t)(row0 + r) * DDIM + t * BK + q * 8
          : Kb + (size_t)(col0 + r - BM) * DDIM + t * BK + q * 8;
      gld_lds16(src, &smem[sl][(c * 256 + wave * 64) * 8]);
    }
  };

  f32x4 acc[4][4];
  #pragma unroll
  for (int i = 0; i < 4; i++)
    #pragma unroll
    for (int j = 0; j < 4; j++) acc[i][j] = {0.f, 0.f, 0.f, 0.f};

  stage(0, 0);
  stage(1, 1);
  VMCNT8();
  BARRIER();

  for (int t = 0; t < NT; t++) {
    const int sl = t & 1;
    const short* As = smem[sl];
    const short* Bs = smem[sl] + BM * BK;

    s16x8 af[2][4], bf[2][4];
    #pragma unroll
    for (int h = 0; h < 2; h++) {
      #pragma unroll
      for (int i = 0; i < 4; i++) {
        const int row = wm * 64 + i * 16 + lr;
        const int ch = (h * 4 + quad) ^ (row & 7);
        af[h][i] = *reinterpret_cast<const s16x8*>(&As[(row * 8 + ch) * 8]);
      }
      #pragma unroll
      for (int j = 0; j < 4; j++) {
        const int row = wn * 64 + j * 16 + lr;
        const int ch = (h * 4 + quad) ^ (row & 7);
        bf[h][j] = *reinterpret_cast<const s16x8*>(&Bs[(row * 8 + ch) * 8]);
      }
    }
    LGKMCNT0();
    __builtin_amdgcn_sched_barrier(0);
    BARRIER();                                   // slot sl reusable block-wide

    const bool pf = (t + 2) < NT;
    if (pf) stage(t + 2, sl);

    __builtin_amdgcn_s_setprio(1);
    #pragma unroll
    for (int h = 0; h < 2; h++)
      #pragma unroll
      for (int i = 0; i < 4; i++)
        #pragma unroll
        for (int j = 0; j < 4; j++)
          acc[i][j] = __builtin_amdgcn_mfma_f32_16x16x32_bf16(
              af[h][i], bf[h][j], acc[i][j], 0, 0, 0);
    __builtin_amdgcn_s_setprio(0);

    if (pf) { VMCNT8(); } else { VMCNT0(); }
    BARRIER();
  }

  constexpr float scale = 0.03125f;
  #pragma unroll
  for (int i = 0; i < 4; i++) {
    const int r0 = row0 + wm * 64 + i * 16 + quad * 4;
    float ex[4][4];
    #pragma unroll
    for (int j = 0; j < 4; j++) {
      const int c = col0 + wn * 64 + j * 16 + lr;
      #pragma unroll
      for (int r = 0; r < 4; r++) {
        ex[j][r] = __expf(acc[i][j][r] * scale);
        SP[(size_t)(r0 + r) * N_TOK + c] = f2b(ex[j][r]);
      }
    }
    #pragma unroll
    for (int r = 0; r < 4; r++) {
      float s = 0.f;
      #pragma unroll
      for (int j = 0; j < 4; j++) s += ex[j][r];
      s += __shfl_xor(s, 1, 64);
      s += __shfl_xor(s, 2, 64);
      s += __shfl_xor(s, 4, 64);
      s += __shfl_xor(s, 8, 64);
      if (lr == 0) atomicAdd(&rowsum[r0 + r], s);
    }
  }
}

// ---------------------------------------------------------------------------
// R17 k_pv: 128x64 tile, BK=64, counted-vmcnt double-buffer (R16 schedule).
// Grid (16,32)=512 = 2 blk/CU; LDS 2 x 24KB = 48KB; 6 loads/thr/tile, vmcnt(6).
// ---------------------------------------------------------------------------
__global__ __launch_bounds__(256, 2)
void k_pv(const short* __restrict__ SP, const short* __restrict__ Vt,
          float* __restrict__ out, const float* __restrict__ rowsum)
{
  constexpr int BM = 128, BN = 64, BK = 64;
  constexpr int NT = N_TOK / BK;                // 64 K-tiles
  __shared__ short smem[2][(BM + BN) * BK];     // 2 x 12288 shorts = 48 KiB

  int bx = blockIdx.x, by = blockIdx.y;
  xcd_remap(DDIM / 64, bx, by);
  const int row0 = by * BM, col0 = bx * BN;

  const int tid  = threadIdx.x;
  const int wave = tid >> 6, lane = tid & 63;
  const int wm = wave >> 1, wn = wave & 1;      // 2x2 waves, 64x32 out each
  const int quad = lane >> 4, lr = lane & 15;

  auto stage = [&](int t, int sl) {
    #pragma unroll
    for (int c = 0; c < 6; c++) {
      const int id = c * 256 + tid;             // 0..1535
      const int r  = id >> 3;                   // rows 0..191 (A:0-127, B:128-191)
      const int q  = (id & 7) ^ (r & 7);
      const short* src = (r < BM)
          ? SP + (size_t)(row0 + r) * N_TOK + t * BK + q * 8
          : Vt + (size_t)(col0 + r - BM) * N_TOK + t * BK + q * 8;
      gld_lds16(src, &smem[sl][(c * 256 + wave * 64) * 8]);
    }
  };

  f32x4 acc[4][2];
  #pragma unroll
  for (int i = 0; i < 4; i++)
    #pragma unroll
    for (int j = 0; j < 2; j++) acc[i][j] = {0.f, 0.f, 0.f, 0.f};

  stage(0, 0);
  stage(1, 1);
  VMCNT6();
  BARRIER();

  for (int t = 0; t < NT; t++) {
    const int sl = t & 1;
    const short* As = smem[sl];
    const short* Bs = smem[sl] + BM * BK;

    s16x8 af[2][4], bf[2][2];
    #pragma unroll
    for (int h = 0; h < 2; h++) {
      #pragma unroll
      for (int i = 0; i < 4; i++) {
        const int row = wm * 64 + i * 16 + lr;
        const int ch = (h * 4 + quad) ^ (row & 7);
        af[h][i] = *reinterpret_cast<const s16x8*>(&As[(row * 8 + ch) * 8]);
      }
      #pragma unroll
      for (int j = 0; j < 2; j++) {
        const int row = wn * 32 + j * 16 + lr;
        const int ch = (h * 4 + quad) ^ (row & 7);
        bf[h][j] = *reinterpret_cast<const s16x8*>(&Bs[(row * 8 + ch) * 8]);
      }
    }
    LGKMCNT0();
    __builtin_amdgcn_sched_barrier(0);
    BARRIER();                                   // slot sl reusable block-wide

    const bool pf = (t + 2) < NT;
    if (pf) stage(t + 2, sl);

    __builtin_amdgcn_s_setprio(1);
    #pragma unroll
    for (int h = 0; h < 2; h++)
      #pragma unroll
      for (int i = 0; i < 4; i++)
        #pragma unroll
        for (int j = 0; j < 2; j++)
          acc[i][j] = __builtin_amdgcn_mfma_f32_16x16x32_bf16(
              af[h][i], bf[h][j], acc[i][j], 0, 0, 0);
    __builtin_amdgcn_s_setprio(0);

    if (pf) { VMCNT6(); } else { VMCNT0(); }
    BARRIER();
  }

  // epilogue: O = acc / rowsum[row], fp32 coalesced store
  #pragma unroll
  for (int i = 0; i < 4; i++) {
    const int r0 = row0 + wm * 64 + i * 16 + quad * 4;
    float linv[4];
    #pragma unroll
    for (int r = 0; r < 4; r++) linv[r] = 1.0f / rowsum[r0 + r];
    #pragma unroll
    for (int j = 0; j < 2; j++) {
      const int c = col0 + wn * 32 + j * 16 + lr;
      #pragma unroll
      for (int r = 0; r < 4; r++)
        out[(size_t)(r0 + r) * DDIM + c] = acc[i][j][r] * linv[r];
    }
  }
}

// ---------------------------------------------------------------------------
extern "C" void kernel_launch(void* const* d_in, const int* in_sizes, int n_in,
                              void* d_out, int out_size, void* d_ws, size_t ws_size,
                              hipStream_t stream)
{
  const float* x  = (const float*)d_in[0];
  const float* Wq = (const float*)d_in[1];
  const float* bq = (const float*)d_in[2];
  const float* Wk = (const float*)d_in[3];
  const float* bk = (const float*)d_in[4];
  const float* Wv = (const float*)d_in[5];
  const float* bv = (const float*)d_in[6];
  float* out = (float*)d_out;

  char* ws = (char*)d_ws;
  const size_t MB = 1024 * 1024;
  short* Qb  = (short*)(ws + 0 * MB);
  short* Kb  = (short*)(ws + 8 * MB);
  short* Vt  = (short*)(ws + 24 * MB);
  short* SP  = (short*)(ws + 32 * MB);   // 32 MB (32..64MB)
  short* xb  = (short*)(ws + 32 * MB);   // overlaps SP (dead before k_score)
  short* Wqb = (short*)(ws + 40 * MB);
  short* Wkb = (short*)(ws + 42 * MB);
  short* Wvb = (short*)(ws + 44 * MB);
  float* rowsum = (float*)(ws + 64 * MB); // past SP (ws >= 112MB, proven R3)

  dim3 b256(256);

  // fp32 -> bf16 for x and the three W's + zero rowsum (one extra block)
  cvt_all<<<dim3(NCVT + 1), b256, 0, stream>>>(
      x, Wq, Wk, Wv, xb, Wqb, Wkb, Wvb, rowsum);

  // Q/K = x @ W^T + b (bf16); V-slice writes Vt transposed; dbuf-pipelined
  k_qkv<<<dim3(DDIM / 128, N_TOK / 128, 3), b256, 0, stream>>>(
      xb, Wqb, Wkb, Wvb, bq, bk, bv, Qb, Kb, Vt);

  // P = exp(Q @ K^T / 32) (bf16) + rowsum atomics; dbuf-pipelined 128x128
  k_score<<<dim3(32, 32), b256, 0, stream>>>(Qb, Kb, SP, rowsum);

  // O = (P @ Vt^T) / rowsum (fp32 out), dbuf-pipelined 128x64 BK=64
  k_pv<<<dim3(DDIM / 64, N_TOK / 128), b256, 0, stream>>>(
      SP, Vt, out, rowsum);
}

// Round 7
// 196.785 us; speedup vs baseline: 1.2454x; 1.0049x over previous
//
#include <hip/hip_runtime.h>

// N=4096, D=1024 self-attention, all GEMMs NT-form bf16 MFMA (16x16x32), fp32 acc.
// R4: BK=64 + XOR swizzle -> 0 bank conflicts. R5: XCD swizzle.
// R7: softmax fused into k_score/k_pv epilogues. R12: V-transpose in k_qkv.
// R14 (REVERTED): BK=32 ring. R15 (REVERTED): split-K atomics.
// R16 (WIN, 213->207): k_score counted-vmcnt double-buffer (T3+T4+T5).
// R17 (WIN, 207->200): same pipeline on k_pv. R18 (WIN, 200->197.7): on k_qkv.
// R19: k_score rebuilt as the m201-style 8-phase 256x256 schedule:
//   512 thr (8 waves 2Mx4N), BK=64, 2 K-tiles/iter, 8 phases/iter, each
//   {ds_read quadrant ∥ stage 1 half-tile -> barrier -> lgkm0 -> 16 MFMA ->
//   barrier}; vmcnt(4) only at phases 3/7. FIFO ledger + half-tile free/
//   deadline analysis in session notes; prologue = t0 x4 + t1.{H2,H0}.
//   LDS 128KB static, grid 16x16=256 = 1 blk/CU.
// R20: R19 resubmission -- R6 bench died with "container failed twice"
//   (infra-level, no pytest/compile/profile output). Ledger re-audited:
//   uniform barriers, FIFO drain counts, overwrite deadlines all check out.
//   No code change.
//
// ws layout:
//   Qb bf16[4096,1024] @ 0      Kb @ 8MB     Vt bf16[1024,4096] @ 24MB
//   SP bf16[4096,4096] @ 32MB   (exp'd scores; spans 32..64MB)
//   xb @ 32MB (overlaps SP; dead before k_score), Wqb @ 40MB, Wkb @ 42MB, Wvb @ 44MB
//   rowsum fp32[4096] @ 64MB    (past SP; ws_size >= 112MB proven in R3)

#define N_TOK 4096
#define DDIM  1024

typedef short s16x4 __attribute__((ext_vector_type(4)));
typedef short s16x8 __attribute__((ext_vector_type(8)));
typedef float f32x4 __attribute__((ext_vector_type(4)));

#define VMCNT0() asm volatile("s_waitcnt vmcnt(0)" ::: "memory")
#define VMCNT4() asm volatile("s_waitcnt vmcnt(4)" ::: "memory")
#define VMCNT6() asm volatile("s_waitcnt vmcnt(6)" ::: "memory")
#define VMCNT8() asm volatile("s_waitcnt vmcnt(8)" ::: "memory")
#define LGKMCNT0() asm volatile("s_waitcnt lgkmcnt(0)" ::: "memory")
#define SCHEDB() __builtin_amdgcn_sched_barrier(0)
#define BARRIER() do { asm volatile("" ::: "memory"); \
                       __builtin_amdgcn_s_barrier();  \
                       asm volatile("" ::: "memory"); } while (0)

__device__ inline short f2b(float f) {
  unsigned int u = __float_as_uint(f);
  unsigned int r = (u + 0x7FFFu + ((u >> 16) & 1u)) >> 16;
  return (short)(unsigned short)r;
}

__device__ __forceinline__ void gld_lds16(const short* g, short* l) {
  __builtin_amdgcn_global_load_lds(
      (const __attribute__((address_space(1))) unsigned int*)g,
      (__attribute__((address_space(3))) unsigned int*)l, 16, 0, 0);
}

// XCD-locality remap, GY=32 grids: XCD (L%8) owns a 4-row-tile band.
__device__ __forceinline__ void xcd_remap(int gx, int& bx, int& by) {
  const int L = by * gx + bx;
  const int g = L & 7, h = L >> 3;
  by = g * 4 + (h & 3);
  bx = h >> 2;
}
// 256-tile variant: XCD owns a 2-row-tile band.
__device__ __forceinline__ void xcd_remap16(int gx, int& bx, int& by) {
  const int L = by * gx + bx;
  const int g = L & 7, h = L >> 3;
  by = g * 2 + (h & 1);
  bx = h >> 1;
}

// ---------------------------------------------------------------------------
// R18 pipelined 128x128 BK=64 NT GEMM (R16 schedule). MODE epilogues:
//   0: bf16 store of scale*acc + bias                  (aux = bias)
//   3: bf16 TRANSPOSED store of acc + bias             (aux = bias)
// smem: 2 slots x 16384 shorts (64 KiB). ldA == ldB == ld.
// ---------------------------------------------------------------------------
template<int MODE>
__device__ __forceinline__ void gemm_pipe128(
    const short* __restrict__ A, const short* __restrict__ B,
    void* __restrict__ C, const float* __restrict__ aux,
    short (*smem)[(128 + 128) * 64],
    int K, int ld, int ldc, float scale, int row0, int col0)
{
  constexpr int BM = 128, BN = 128, BK = 64;
  const int NT = K / BK;

  const int tid  = threadIdx.x;
  const int wave = tid >> 6, lane = tid & 63;
  const int wm = wave >> 1, wn = wave & 1;      // 2x2 waves, 64x64 out each
  const int quad = lane >> 4, lr = lane & 15;

  auto stage = [&](int t, int sl) {
    #pragma unroll
    for (int c = 0; c < 8; c++) {
      const int id = c * 256 + tid;             // 0..2047
      const int r  = id >> 3;                   // rows 0..255 (A:0-127, B:128-255)
      const int q  = (id & 7) ^ (r & 7);
      const short* src = (r < BM)
          ? A + (size_t)(row0 + r) * ld + t * BK + q * 8
          : B + (size_t)(col0 + r - BM) * ld + t * BK + q * 8;
      gld_lds16(src, &smem[sl][(c * 256 + wave * 64) * 8]);
    }
  };

  f32x4 acc[4][4];
  #pragma unroll
  for (int i = 0; i < 4; i++)
    #pragma unroll
    for (int j = 0; j < 4; j++) acc[i][j] = {0.f, 0.f, 0.f, 0.f};

  stage(0, 0);
  stage(1, 1);
  VMCNT8();
  BARRIER();

  for (int t = 0; t < NT; t++) {
    const int sl = t & 1;
    const short* As = smem[sl];
    const short* Bs = smem[sl] + BM * BK;

    s16x8 af[2][4], bf[2][4];
    #pragma unroll
    for (int h = 0; h < 2; h++) {
      #pragma unroll
      for (int i = 0; i < 4; i++) {
        const int row = wm * 64 + i * 16 + lr;
        const int ch = (h * 4 + quad) ^ (row & 7);
        af[h][i] = *reinterpret_cast<const s16x8*>(&As[(row * 8 + ch) * 8]);
      }
      #pragma unroll
      for (int j = 0; j < 4; j++) {
        const int row = wn * 64 + j * 16 + lr;
        const int ch = (h * 4 + quad) ^ (row & 7);
        bf[h][j] = *reinterpret_cast<const s16x8*>(&Bs[(row * 8 + ch) * 8]);
      }
    }
    LGKMCNT0();
    SCHEDB();
    BARRIER();                                   // slot sl reusable block-wide

    const bool pf = (t + 2) < NT;
    if (pf) stage(t + 2, sl);

    __builtin_amdgcn_s_setprio(1);
    #pragma unroll
    for (int h = 0; h < 2; h++)
      #pragma unroll
      for (int i = 0; i < 4; i++)
        #pragma unroll
        for (int j = 0; j < 4; j++)
          acc[i][j] = __builtin_amdgcn_mfma_f32_16x16x32_bf16(
              af[h][i], bf[h][j], acc[i][j], 0, 0, 0);
    __builtin_amdgcn_s_setprio(0);

    if (pf) { VMCNT8(); } else { VMCNT0(); }
    BARRIER();
  }
  // loop exit: all LDS reads drained (tail vmcnt(0)+barrier) -> smem reusable.

  if constexpr (MODE == 0) {
    float bb[4];
    #pragma unroll
    for (int j = 0; j < 4; j++) bb[j] = aux[col0 + wn * 64 + j * 16 + lr];
    #pragma unroll
    for (int i = 0; i < 4; i++) {
      const int r0 = row0 + wm * 64 + i * 16 + quad * 4;
      #pragma unroll
      for (int j = 0; j < 4; j++) {
        const int c = col0 + wn * 64 + j * 16 + lr;
        #pragma unroll
        for (int r = 0; r < 4; r++)
          ((short*)C)[(size_t)(r0 + r) * ldc + c] = f2b(acc[i][j][r] * scale + bb[j]);
      }
    }
  } else {
    // MODE 3: transposed bf16 store with bias. trans[col][row], stride 136.
    float bb[4];
    #pragma unroll
    for (int j = 0; j < 4; j++) bb[j] = aux[col0 + wn * 64 + j * 16 + lr];
    short* trans = &smem[0][0];                  // 128 x 136 shorts = 34816 B
    #pragma unroll
    for (int i = 0; i < 4; i++) {
      const int rl = wm * 64 + i * 16 + quad * 4;
      #pragma unroll
      for (int j = 0; j < 4; j++) {
        const int cl = wn * 64 + j * 16 + lr;
        s16x4 v;
        #pragma unroll
        for (int r = 0; r < 4; r++) v[r] = f2b(acc[i][j][r] * scale + bb[j]);
        *reinterpret_cast<s16x4*>(&trans[cl * 136 + rl]) = v;
      }
    }
    BARRIER();
    #pragma unroll
    for (int s = 0; s < 8; s++) {
      const int u = s * 256 + tid;
      const int cc = u >> 4;                     // column 0..127
      const int seg = u & 15;                    // 16 segs x 8 shorts = 128 rows
      s16x8 v = *reinterpret_cast<const s16x8*>(&trans[cc * 136 + seg * 8]);
      *reinterpret_cast<s16x8*>(
          &((short*)C)[(size_t)(col0 + cc) * ldc + row0 + seg * 8]) = v;
    }
  }
}

// ---------------------------------------------------------------------------
// fp32 -> bf16 conversion for x, Wq, Wk, Wv + rowsum zeroing (one launch).
// ---------------------------------------------------------------------------
#define XU  (N_TOK * DDIM / 8)      // 524288
#define WU  (DDIM * DDIM / 8)       // 131072
#define NCVT ((XU + 3 * WU) / 256)  // 3584 convert blocks
__global__ __launch_bounds__(256)
void cvt_all(const float* __restrict__ x,  const float* __restrict__ wq,
             const float* __restrict__ wk, const float* __restrict__ wv,
             short* __restrict__ xb, short* __restrict__ wqb,
             short* __restrict__ wkb, short* __restrict__ wvb,
             float* __restrict__ rowsum)
{
  if (blockIdx.x >= NCVT) {
    float4 z = {0.f, 0.f, 0.f, 0.f};
    float4* p = reinterpret_cast<float4*>(rowsum) + threadIdx.x * 4;
    p[0] = z; p[1] = z; p[2] = z; p[3] = z;
    return;
  }
  int gid = blockIdx.x * 256 + threadIdx.x;
  const float* src; short* dst; int off;
  if (gid < XU)               { src = x;  dst = xb;  off = gid; }
  else if (gid < XU + WU)     { src = wq; dst = wqb; off = gid - XU; }
  else if (gid < XU + 2 * WU) { src = wk; dst = wkb; off = gid - XU - WU; }
  else                        { src = wv; dst = wvb; off = gid - XU - 2 * WU; }
  const float4* g = reinterpret_cast<const float4*>(src) + (size_t)off * 2;
  float4 a = g[0], b = g[1];
  s16x8 o;
  o[0] = f2b(a.x); o[1] = f2b(a.y); o[2] = f2b(a.z); o[3] = f2b(a.w);
  o[4] = f2b(b.x); o[5] = f2b(b.y); o[6] = f2b(b.z); o[7] = f2b(b.w);
  reinterpret_cast<s16x8*>(dst)[off] = o;
}

// ---------------------------------------------------------------------------
// R18 k_qkv: pipelined 128x128 BK=64; grid (8,32,3); LDS 64KB -> 2 blk/CU.
// ---------------------------------------------------------------------------
__global__ __launch_bounds__(256, 2)
void k_qkv(const short* __restrict__ xb,
           const short* __restrict__ Wqb, const short* __restrict__ Wkb,
           const short* __restrict__ Wvb,
           const float* __restrict__ bq, const float* __restrict__ bk,
           const float* __restrict__ bv,
           short* __restrict__ Qb, short* __restrict__ Kb, short* __restrict__ Vt)
{
  __shared__ short smem[2][(128 + 128) * 64];   // 64 KiB
  int bx = blockIdx.x, by = blockIdx.y;
  xcd_remap(DDIM / 128, bx, by);
  if (blockIdx.z == 0) {
    gemm_pipe128<0>(xb, Wqb, Qb, bq, smem, DDIM, DDIM, DDIM,
                    1.0f, by * 128, bx * 128);
  } else if (blockIdx.z == 1) {
    gemm_pipe128<0>(xb, Wkb, Kb, bk, smem, DDIM, DDIM, DDIM,
                    1.0f, by * 128, bx * 128);
  } else {
    gemm_pipe128<3>(xb, Wvb, Vt, bv, smem, DDIM, DDIM, N_TOK,
                    1.0f, by * 128, bx * 128);
  }
}

// ---------------------------------------------------------------------------
// R19/R20 k_score: 8-phase 256x256 BK=64 schedule (m201-style), 512 threads.
// 8 waves (2M x 4N), per-wave C = 128x64 (acc[8][4]). LDS 2 x 64KB = 128KB.
// Halves: 0 = A rows 0-127, 1 = A rows 128-255, 2 = B rows 0-127, 3 = B 128-255.
// Phase order per K-tile: (mh,nh) = (0,0),(0,1),(1,1),(1,0); reads 12/4/8/0.
// Stage plan per iter i (tiles 2i,2i+1 resident; t1 = 2i+1):
//   p0: t1.H3->buf1   p1: t1.H1->buf1   p2: (t1+1).H2->buf0  p3: (t1+1).H0->buf0
//   p4: (t1+1).H3     p5: (t1+1).H1     p6: (t1+2).H2->buf1  p7: (t1+2).H0->buf1
// vmcnt(4) at p3 drains all of buf1's tile before p4 reads it; at p7 drains
// buf0's next tile before next-iter p0. Last iter: vmcnt(0) at p3.
// ---------------------------------------------------------------------------
#define READ_AF(As, MH) do {                                                  \
    _Pragma("unroll")                                                         \
    for (int kh = 0; kh < 2; kh++)                                            \
      _Pragma("unroll")                                                       \
      for (int f = 0; f < 4; f++) {                                           \
        const int row_ = wm * 128 + (MH) * 64 + f * 16 + lr;                  \
        const int ch_ = (kh * 4 + quad) ^ (row_ & 7);                         \
        af[kh][f] = *reinterpret_cast<const s16x8*>(&(As)[(row_ * 8 + ch_) * 8]); \
      }                                                                       \
  } while (0)

#define READ_BF(Bs, NH, BF) do {                                              \
    _Pragma("unroll")                                                         \
    for (int kh = 0; kh < 2; kh++)                                            \
      _Pragma("unroll")                                                       \
      for (int g = 0; g < 2; g++) {                                           \
        const int row_ = wn * 64 + (NH) * 32 + g * 16 + lr;                   \
        const int ch_ = (kh * 4 + quad) ^ (row_ & 7);                         \
        BF[kh][g] = *reinterpret_cast<const s16x8*>(&(Bs)[(row_ * 8 + ch_) * 8]); \
      }                                                                       \
  } while (0)

#define MFMA_Q(MH, NH, BF) do {                                               \
    __builtin_amdgcn_s_setprio(1);                                            \
    _Pragma("unroll")                                                         \
    for (int kh = 0; kh < 2; kh++)                                            \
      _Pragma("unroll")                                                       \
      for (int f = 0; f < 4; f++)                                             \
        _Pragma("unroll")                                                     \
        for (int g = 0; g < 2; g++)                                           \
          acc[(MH) * 4 + f][(NH) * 2 + g] =                                   \
              __builtin_amdgcn_mfma_f32_16x16x32_bf16(                        \
                  af[kh][f], BF[kh][g], acc[(MH) * 4 + f][(NH) * 2 + g],      \
                  0, 0, 0);                                                   \
    __builtin_amdgcn_s_setprio(0);                                            \
  } while (0)

__global__ __launch_bounds__(512, 2)
void k_score(const short* __restrict__ Qb, const short* __restrict__ Kb,
             short* __restrict__ SP, float* __restrict__ rowsum)
{
  constexpr int NITER = 8;                      // 16 K-tiles, 2 per iter
  __shared__ short smem[2][32768];              // [buf][A 256x64 | B 256x64] 128KB

  int bx = blockIdx.x, by = blockIdx.y;
  xcd_remap16(16, bx, by);
  const int row0 = by * 256, col0 = bx * 256;

  const int tid  = threadIdx.x;
  const int wave = tid >> 6, lane = tid & 63;
  const int wm = wave >> 2, wn = wave & 3;      // 2x4 waves, 128x64 of C each
  const int quad = lane >> 4, lr = lane & 15;

  // stage one 16KB half-tile: 2 x gld_lds16 per thread
  auto stage_h = [&](int t, int b, int h) {
    const short* gbase = (h < 2)
        ? Qb + (size_t)(row0 + (h & 1) * 128) * DDIM
        : Kb + (size_t)(col0 + (h & 1) * 128) * DDIM;
    short* dst = &smem[b][(h >> 1) * 16384 + (h & 1) * 8192];
    #pragma unroll
    for (int c = 0; c < 2; c++) {
      const int id = c * 512 + tid;             // 0..1023
      const int r  = id >> 3;                   // 0..127
      const int q  = (id & 7) ^ (r & 7);
      gld_lds16(gbase + (size_t)r * DDIM + t * 64 + q * 8,
                dst + (c * 512 + wave * 64) * 8);
    }
  };

  s16x8 af[2][4], bf0[2][2], bf1[2][2];
  f32x4 acc[8][4];
  #pragma unroll
  for (int i = 0; i < 8; i++)
    #pragma unroll
    for (int j = 0; j < 4; j++) acc[i][j] = {0.f, 0.f, 0.f, 0.f};

  const short* As0 = smem[0];
  const short* Bs0 = smem[0] + 16384;
  const short* As1 = smem[1];
  const short* Bs1 = smem[1] + 16384;

  // prologue: t0 fully, t1.{H2,H0}; vmcnt(4) leaves t1.{H2,H0} in flight,
  // matching the steady-state invariant entering p0.
  stage_h(0, 0, 2); stage_h(0, 0, 3); stage_h(0, 0, 0); stage_h(0, 0, 1);
  stage_h(1, 1, 2); stage_h(1, 1, 0);
  VMCNT4();
  BARRIER();

  for (int i = 0; i < NITER; i++) {
    const int t1 = 2 * i + 1;
    const bool more = (i + 1) < NITER;

    // p0: buf0 (mh0,nh0) -- 12 reads
    READ_AF(As0, 0); READ_BF(Bs0, 0, bf0);
    stage_h(t1, 1, 3);
    BARRIER(); LGKMCNT0(); SCHEDB();
    MFMA_Q(0, 0, bf0);
    BARRIER();
    // p1: (mh0,nh1) -- 4 reads
    READ_BF(Bs0, 1, bf1);
    stage_h(t1, 1, 1);
    BARRIER(); LGKMCNT0(); SCHEDB();
    MFMA_Q(0, 1, bf1);
    BARRIER();
    // p2: (mh1,nh1) -- 8 reads
    READ_AF(As0, 1);
    if (more) stage_h(t1 + 1, 0, 2);
    BARRIER(); LGKMCNT0(); SCHEDB();
    MFMA_Q(1, 1, bf1);
    BARRIER();
    // p3: (mh1,nh0) -- 0 reads; drain buf1's tile (t1) before p4 reads it
    if (more) { stage_h(t1 + 1, 0, 0); VMCNT4(); } else { VMCNT0(); }
    BARRIER();
    MFMA_Q(1, 0, bf0);
    BARRIER();
    // p4: buf1 (mh0,nh0) -- 12 reads
    READ_AF(As1, 0); READ_BF(Bs1, 0, bf0);
    if (more) stage_h(t1 + 1, 0, 3);
    BARRIER(); LGKMCNT0(); SCHEDB();
    MFMA_Q(0, 0, bf0);
    BARRIER();
    // p5: (mh0,nh1)
    READ_BF(Bs1, 1, bf1);
    if (more) stage_h(t1 + 1, 0, 1);
    BARRIER(); LGKMCNT0(); SCHEDB();
    MFMA_Q(0, 1, bf1);
    BARRIER();
    // p6: (mh1,nh1)
    READ_AF(As1, 1);
    if (more) stage_h(t1 + 2, 1, 2);
    BARRIER(); LGKMCNT0(); SCHEDB();
    MFMA_Q(1, 1, bf1);
    BARRIER();
    // p7: (mh1,nh0) -- drain buf0's next tile before next-iter p0
    if (more) { stage_h(t1 + 2, 1, 0); VMCNT4(); } else { VMCNT0(); }
    BARRIER();
    MFMA_Q(1, 0, bf0);
    BARRIER();
  }

  // epilogue: P = exp(scale*acc), bf16 store + rowsum atomics
  constexpr float scale = 0.03125f;
  #pragma unroll
  for (int i = 0; i < 8; i++) {
    const int r0 = row0 + wm * 128 + i * 16 + quad * 4;
    float ex[4][4];
    #pragma unroll
    for (int j = 0; j < 4; j++) {
      const int c = col0 + wn * 64 + j * 16 + lr;
      #pragma unroll
      for (int r = 0; r < 4; r++) {
        ex[j][r] = __expf(acc[i][j][r] * scale);
        SP[(size_t)(r0 + r) * N_TOK + c] = f2b(ex[j][r]);
      }
    }
    #pragma unroll
    for (int r = 0; r < 4; r++) {
      float s = 0.f;
      #pragma unroll
      for (int j = 0; j < 4; j++) s += ex[j][r];
      s += __shfl_xor(s, 1, 64);
      s += __shfl_xor(s, 2, 64);
      s += __shfl_xor(s, 4, 64);
      s += __shfl_xor(s, 8, 64);
      if (lr == 0) atomicAdd(&rowsum[r0 + r], s);
    }
  }
}

// ---------------------------------------------------------------------------
// R17 k_pv: 128x64 tile, BK=64, counted-vmcnt double-buffer (R16 schedule).
// Grid (16,32)=512 = 2 blk/CU; LDS 2 x 24KB = 48KB; 6 loads/thr/tile, vmcnt(6).
// ---------------------------------------------------------------------------
__global__ __launch_bounds__(256, 2)
void k_pv(const short* __restrict__ SP, const short* __restrict__ Vt,
          float* __restrict__ out, const float* __restrict__ rowsum)
{
  constexpr int BM = 128, BN = 64, BK = 64;
  constexpr int NT = N_TOK / BK;                // 64 K-tiles
  __shared__ short smem[2][(BM + BN) * BK];     // 2 x 12288 shorts = 48 KiB

  int bx = blockIdx.x, by = blockIdx.y;
  xcd_remap(DDIM / 64, bx, by);
  const int row0 = by * BM, col0 = bx * BN;

  const int tid  = threadIdx.x;
  const int wave = tid >> 6, lane = tid & 63;
  const int wm = wave >> 1, wn = wave & 1;      // 2x2 waves, 64x32 out each
  const int quad = lane >> 4, lr = lane & 15;

  auto stage = [&](int t, int sl) {
    #pragma unroll
    for (int c = 0; c < 6; c++) {
      const int id = c * 256 + tid;             // 0..1535
      const int r  = id >> 3;                   // rows 0..191 (A:0-127, B:128-191)
      const int q  = (id & 7) ^ (r & 7);
      const short* src = (r < BM)
          ? SP + (size_t)(row0 + r) * N_TOK + t * BK + q * 8
          : Vt + (size_t)(col0 + r - BM) * N_TOK + t * BK + q * 8;
      gld_lds16(src, &smem[sl][(c * 256 + wave * 64) * 8]);
    }
  };

  f32x4 acc[4][2];
  #pragma unroll
  for (int i = 0; i < 4; i++)
    #pragma unroll
    for (int j = 0; j < 2; j++) acc[i][j] = {0.f, 0.f, 0.f, 0.f};

  stage(0, 0);
  stage(1, 1);
  VMCNT6();
  BARRIER();

  for (int t = 0; t < NT; t++) {
    const int sl = t & 1;
    const short* As = smem[sl];
    const short* Bs = smem[sl] + BM * BK;

    s16x8 af[2][4], bf[2][2];
    #pragma unroll
    for (int h = 0; h < 2; h++) {
      #pragma unroll
      for (int i = 0; i < 4; i++) {
        const int row = wm * 64 + i * 16 + lr;
        const int ch = (h * 4 + quad) ^ (row & 7);
        af[h][i] = *reinterpret_cast<const s16x8*>(&As[(row * 8 + ch) * 8]);
      }
      #pragma unroll
      for (int j = 0; j < 2; j++) {
        const int row = wn * 32 + j * 16 + lr;
        const int ch = (h * 4 + quad) ^ (row & 7);
        bf[h][j] = *reinterpret_cast<const s16x8*>(&Bs[(row * 8 + ch) * 8]);
      }
    }
    LGKMCNT0();
    SCHEDB();
    BARRIER();                                   // slot sl reusable block-wide

    const bool pf = (t + 2) < NT;
    if (pf) stage(t + 2, sl);

    __builtin_amdgcn_s_setprio(1);
    #pragma unroll
    for (int h = 0; h < 2; h++)
      #pragma unroll
      for (int i = 0; i < 4; i++)
        #pragma unroll
        for (int j = 0; j < 2; j++)
          acc[i][j] = __builtin_amdgcn_mfma_f32_16x16x32_bf16(
              af[h][i], bf[h][j], acc[i][j], 0, 0, 0);
    __builtin_amdgcn_s_setprio(0);

    if (pf) { VMCNT6(); } else { VMCNT0(); }
    BARRIER();
  }

  // epilogue: O = acc / rowsum[row], fp32 coalesced store
  #pragma unroll
  for (int i = 0; i < 4; i++) {
    const int r0 = row0 + wm * 64 + i * 16 + quad * 4;
    float linv[4];
    #pragma unroll
    for (int r = 0; r < 4; r++) linv[r] = 1.0f / rowsum[r0 + r];
    #pragma unroll
    for (int j = 0; j < 2; j++) {
      const int c = col0 + wn * 32 + j * 16 + lr;
      #pragma unroll
      for (int r = 0; r < 4; r++)
        out[(size_t)(r0 + r) * DDIM + c] = acc[i][j][r] * linv[r];
    }
  }
}

// ---------------------------------------------------------------------------
extern "C" void kernel_launch(void* const* d_in, const int* in_sizes, int n_in,
                              void* d_out, int out_size, void* d_ws, size_t ws_size,
                              hipStream_t stream)
{
  const float* x  = (const float*)d_in[0];
  const float* Wq = (const float*)d_in[1];
  const float* bq = (const float*)d_in[2];
  const float* Wk = (const float*)d_in[3];
  const float* bk = (const float*)d_in[4];
  const float* Wv = (const float*)d_in[5];
  const float* bv = (const float*)d_in[6];
  float* out = (float*)d_out;

  char* ws = (char*)d_ws;
  const size_t MB = 1024 * 1024;
  short* Qb  = (short*)(ws + 0 * MB);
  short* Kb  = (short*)(ws + 8 * MB);
  short* Vt  = (short*)(ws + 24 * MB);
  short* SP  = (short*)(ws + 32 * MB);   // 32 MB (32..64MB)
  short* xb  = (short*)(ws + 32 * MB);   // overlaps SP (dead before k_score)
  short* Wqb = (short*)(ws + 40 * MB);
  short* Wkb = (short*)(ws + 42 * MB);
  short* Wvb = (short*)(ws + 44 * MB);
  float* rowsum = (float*)(ws + 64 * MB); // past SP (ws >= 112MB, proven R3)

  dim3 b256(256);

  // fp32 -> bf16 for x and the three W's + zero rowsum (one extra block)
  cvt_all<<<dim3(NCVT + 1), b256, 0, stream>>>(
      x, Wq, Wk, Wv, xb, Wqb, Wkb, Wvb, rowsum);

  // Q/K = x @ W^T + b (bf16); V-slice writes Vt transposed; dbuf-pipelined
  k_qkv<<<dim3(DDIM / 128, N_TOK / 128, 3), b256, 0, stream>>>(
      xb, Wqb, Wkb, Wvb, bq, bk, bv, Qb, Kb, Vt);

  // P = exp(Q @ K^T / 32) (bf16) + rowsum atomics; 8-phase 256x256 schedule
  k_score<<<dim3(16, 16), dim3(512), 0, stream>>>(Qb, Kb, SP, rowsum);

  // O = (P @ Vt^T) / rowsum (fp32 out), dbuf-pipelined 128x64 BK=64
  k_pv<<<dim3(DDIM / 64, N_TOK / 128), b256, 0, stream>>>(
      SP, Vt, out, rowsum);
}